// Round 1
// baseline (1928.034 us; speedup 1.0000x reference)
//
#include <hip/hip_runtime.h>
#include <hip/hip_bf16.h>

// Problem constants (hardcoded; shapes/level_start inputs are compile-time known)
#define NQ   900
#define BB   8
#define DD   256
#define HH   8
#define DH   32
#define LL   4
#define PP   5
#define SS   21760
#define DFF  1024
#define MQ   (NQ*BB)      // 7200 rows for query-side GEMMs
#define MV   (SS*BB)      // 174080 rows for value GEMM

typedef __bf16 bf16_t;
typedef __bf16 bf16x8 __attribute__((ext_vector_type(8)));
typedef float  f32x4  __attribute__((ext_vector_type(4)));

// ---------------------------------------------------------------------------
// Generic GEMM: C[M,N] = A[M,K] @ W[N,K]^T + bias, optional ReLU, OT out dtype.
// 64x64 tile, 256 threads (4 waves, 2x2), K-step 32, bf16 MFMA 16x16x32.
// A layout: row-major [M,K] f32 (converted to bf16 on LDS stage).
// W layout: row-major [N,K] f32 (i.e. B^T, K contiguous) - natural for @W.T.
// ---------------------------------------------------------------------------
template<int EPI, typename OT>
__global__ __launch_bounds__(256) void gemm_bt(
    const float* __restrict__ A, const float* __restrict__ W,
    const float* __restrict__ bias, OT* __restrict__ C,
    int M, int N, int K)
{
  __shared__ bf16_t As[64][40];   // pad to 40 (80B row) keeps 16B alignment
  __shared__ bf16_t Bs[64][40];
  const int tiles_n = (N + 63) >> 6;
  const int tm = blockIdx.x / tiles_n;
  const int tn = blockIdx.x - tm * tiles_n;
  const int m0 = tm << 6, n0 = tn << 6;
  const int t = threadIdx.x;
  const int wave = t >> 6, lane = t & 63;
  const int wr = wave >> 1, wc = wave & 1;
  const int lm = lane & 15, kq = lane >> 4;
  const int r = t >> 2, seg = t & 3;

  f32x4 acc00 = {0.f,0.f,0.f,0.f}, acc01 = {0.f,0.f,0.f,0.f};
  f32x4 acc10 = {0.f,0.f,0.f,0.f}, acc11 = {0.f,0.f,0.f,0.f};

  const int am = m0 + r;
  const int bn = n0 + r;
  const bool a_ok = (am < M), b_ok = (bn < N);
  const float* ap0 = A + (size_t)(a_ok ? am : 0) * K + seg * 8;
  const float* bp0 = W + (size_t)(b_ok ? bn : 0) * K + seg * 8;

  for (int k0 = 0; k0 < K; k0 += 32) {
    float av[8], bv[8];
#pragma unroll
    for (int j = 0; j < 8; ++j) av[j] = a_ok ? ap0[k0 + j] : 0.f;
#pragma unroll
    for (int j = 0; j < 8; ++j) bv[j] = b_ok ? bp0[k0 + j] : 0.f;
    bf16x8 apk, bpk;
#pragma unroll
    for (int j = 0; j < 8; ++j) { apk[j] = (bf16_t)av[j]; bpk[j] = (bf16_t)bv[j]; }
    __syncthreads();
    *(bf16x8*)&As[r][seg * 8] = apk;
    *(bf16x8*)&Bs[r][seg * 8] = bpk;
    __syncthreads();
    bf16x8 a0 = *(const bf16x8*)&As[wr * 32 + lm][kq * 8];
    bf16x8 a1 = *(const bf16x8*)&As[wr * 32 + 16 + lm][kq * 8];
    bf16x8 b0 = *(const bf16x8*)&Bs[wc * 32 + lm][kq * 8];
    bf16x8 b1 = *(const bf16x8*)&Bs[wc * 32 + 16 + lm][kq * 8];
    acc00 = __builtin_amdgcn_mfma_f32_16x16x32_bf16(a0, b0, acc00, 0, 0, 0);
    acc01 = __builtin_amdgcn_mfma_f32_16x16x32_bf16(a0, b1, acc01, 0, 0, 0);
    acc10 = __builtin_amdgcn_mfma_f32_16x16x32_bf16(a1, b0, acc10, 0, 0, 0);
    acc11 = __builtin_amdgcn_mfma_f32_16x16x32_bf16(a1, b1, acc11, 0, 0, 0);
  }
  // epilogue: C/D layout col=lane&15, row=(lane>>4)*4+reg  [m89-verified]
  const int crow = m0 + wr * 32 + kq * 4;
  const int ccol = n0 + wc * 32 + lm;
  const bool c0ok = (ccol < N), c1ok = (ccol + 16 < N);
  const float bias0 = c0ok ? bias[ccol] : 0.f;
  const float bias1 = c1ok ? bias[ccol + 16] : 0.f;
#pragma unroll
  for (int ri = 0; ri < 4; ++ri) {
    int r0 = crow + ri;
    if (r0 < M) {
      if (c0ok) { float v = acc00[ri] + bias0; if (EPI == 1) v = fmaxf(v, 0.f);
                  C[(size_t)r0 * N + ccol] = (OT)v; }
      if (c1ok) { float v = acc01[ri] + bias1; if (EPI == 1) v = fmaxf(v, 0.f);
                  C[(size_t)r0 * N + ccol + 16] = (OT)v; }
    }
    int r1 = crow + 16 + ri;
    if (r1 < M) {
      if (c0ok) { float v = acc10[ri] + bias0; if (EPI == 1) v = fmaxf(v, 0.f);
                  C[(size_t)r1 * N + ccol] = (OT)v; }
      if (c1ok) { float v = acc11[ri] + bias1; if (EPI == 1) v = fmaxf(v, 0.f);
                  C[(size_t)r1 * N + ccol + 16] = (OT)v; }
    }
  }
}

// ---------------------------------------------------------------------------
// elementwise add (float4)
// ---------------------------------------------------------------------------
__global__ __launch_bounds__(256) void add_kernel(
    const float4* __restrict__ a, const float4* __restrict__ b,
    float4* __restrict__ o, int n4)
{
  int i = blockIdx.x * 256 + threadIdx.x;
  if (i < n4) {
    float4 x = a[i], y = b[i];
    float4 z; z.x = x.x + y.x; z.y = x.y + y.y; z.z = x.z + y.z; z.w = x.w + y.w;
    o[i] = z;
  }
}

// ---------------------------------------------------------------------------
// residual + layernorm: out[row] = LN(x[row] + res[row]) * g + b, D=256
// one wave per row, 4 rows per block
// ---------------------------------------------------------------------------
__global__ __launch_bounds__(256) void lnres_kernel(
    const float* __restrict__ x, const float* __restrict__ res,
    const float* __restrict__ g, const float* __restrict__ bta,
    float* __restrict__ out, int rows)
{
  int wave = threadIdx.x >> 6, lane = threadIdx.x & 63;
  int row = blockIdx.x * 4 + wave;
  if (row >= rows) return;
  const float4* xp = (const float4*)(x + (size_t)row * DD);
  const float4* rp = (const float4*)(res + (size_t)row * DD);
  float4 v = xp[lane], rr = rp[lane];
  float a0 = v.x + rr.x, a1 = v.y + rr.y, a2 = v.z + rr.z, a3 = v.w + rr.w;
  float s = a0 + a1 + a2 + a3;
#pragma unroll
  for (int off = 32; off; off >>= 1) s += __shfl_xor(s, off);
  float mean = s * (1.0f / DD);
  float d0 = a0 - mean, d1 = a1 - mean, d2 = a2 - mean, d3 = a3 - mean;
  float vs = d0 * d0 + d1 * d1 + d2 * d2 + d3 * d3;
#pragma unroll
  for (int off = 32; off; off >>= 1) vs += __shfl_xor(vs, off);
  float inv = rsqrtf(vs * (1.0f / DD) + 1e-5f);
  float4 gg = ((const float4*)g)[lane];
  float4 bb = ((const float4*)bta)[lane];
  float4 o;
  o.x = d0 * inv * gg.x + bb.x; o.y = d1 * inv * gg.y + bb.y;
  o.z = d2 * inv * gg.z + bb.z; o.w = d3 * inv * gg.w + bb.w;
  ((float4*)(out + (size_t)row * DD))[lane] = o;
}

// ---------------------------------------------------------------------------
// fused self-attention (flash-style, SIMT): per (b,h), online softmax over 900
// keys in 4 chunks of 225. qk: [7200,512] (qp|kp), vp: [7200,256], sa out same.
// Block: 256 thr = 4 waves; block handles 32 q's (8 per wave).
// ---------------------------------------------------------------------------
#define CK 225
__device__ __forceinline__ void bf2x(unsigned u, float& lo, float& hi) {
  lo = __uint_as_float(u << 16);
  hi = __uint_as_float(u & 0xffff0000u);
}

__global__ __launch_bounds__(256) void attn_kernel(
    const float* __restrict__ qk, const float* __restrict__ vp,
    float* __restrict__ sa)
{
  __shared__ bf16_t Kt[CK * 32];
  __shared__ bf16_t Vt[CK * 32];
  __shared__ float  sbuf[4][CK];
  const int bh = blockIdx.x;
  const int b = bh & 7, h = bh >> 3;
  const int qbase = blockIdx.y * 32;
  const int t = threadIdx.x, wave = t >> 6, lane = t & 63;
  const int dp = (lane & 15) * 2;   // d-pair this lane accumulates
  const int ks = lane >> 4;         // k-subset 0..3
  const float scale = 0.17677669529663687f;  // 1/sqrt(32)

  float m_run[8], l_run[8], a0[8], a1[8];
#pragma unroll
  for (int j = 0; j < 8; ++j) { m_run[j] = -1e30f; l_run[j] = 0.f; a0[j] = 0.f; a1[j] = 0.f; }

  for (int c = 0; c < 4; ++c) {
    const int k0 = c * CK;
    __syncthreads();
    for (int idx = t; idx < CK * 32; idx += 256) {
      int row = idx >> 5, d = idx & 31;
      Kt[idx] = (bf16_t)qk[((size_t)(k0 + row) * BB + b) * 512 + 256 + h * 32 + d];
      Vt[idx] = (bf16_t)vp[((size_t)(k0 + row) * BB + b) * 256 + h * 32 + d];
    }
    __syncthreads();
    for (int j = 0; j < 8; ++j) {
      int q = qbase + wave * 8 + j;
      if (q >= NQ) continue;
      float qv[32];
      const float* qptr = qk + ((size_t)q * BB + b) * 512 + h * 32;
#pragma unroll
      for (int d = 0; d < 32; ++d) qv[d] = qptr[d];
      // scores for this chunk: lane covers k = lane + 64*i
      float sarr[4];
      float lmax = -1e30f;
#pragma unroll
      for (int i = 0; i < 4; ++i) {
        int k = lane + i * 64;
        float sv = -1e30f;
        if (k < CK) {
          const uint4* kr = (const uint4*)&Kt[k * 32];
          float acc = 0.f;
#pragma unroll
          for (int c8 = 0; c8 < 4; ++c8) {
            uint4 kvv = kr[c8];
            float l0,h0,l1,h1,l2,h2,l3,h3;
            bf2x(kvv.x,l0,h0); bf2x(kvv.y,l1,h1); bf2x(kvv.z,l2,h2); bf2x(kvv.w,l3,h3);
            int dd = c8 * 8;
            acc = fmaf(qv[dd+0],l0,acc); acc = fmaf(qv[dd+1],h0,acc);
            acc = fmaf(qv[dd+2],l1,acc); acc = fmaf(qv[dd+3],h1,acc);
            acc = fmaf(qv[dd+4],l2,acc); acc = fmaf(qv[dd+5],h2,acc);
            acc = fmaf(qv[dd+6],l3,acc); acc = fmaf(qv[dd+7],h3,acc);
          }
          sv = acc * scale;
        }
        sarr[i] = sv;
        lmax = fmaxf(lmax, sv);
      }
#pragma unroll
      for (int off = 32; off; off >>= 1) lmax = fmaxf(lmax, __shfl_xor(lmax, off));
      float m_new = fmaxf(m_run[j], lmax);
      float alpha = __expf(m_run[j] - m_new);
      float psum = 0.f;
#pragma unroll
      for (int i = 0; i < 4; ++i) {
        int k = lane + i * 64;
        if (k < CK) {
          float p = __expf(sarr[i] - m_new);
          sbuf[wave][k] = p;
          psum += p;
        }
      }
#pragma unroll
      for (int off = 32; off; off >>= 1) psum += __shfl_xor(psum, off);
      l_run[j] = l_run[j] * alpha + psum;
      m_run[j] = m_new;
      float x0 = 0.f, x1 = 0.f;
      for (int k = ks; k < CK; k += 4) {
        float p = sbuf[wave][k];
        unsigned vv = *(const unsigned*)&Vt[k * 32 + dp];
        float v0, v1; bf2x(vv, v0, v1);
        x0 = fmaf(p, v0, x0);
        x1 = fmaf(p, v1, x1);
      }
      a0[j] = a0[j] * alpha + x0;
      a1[j] = a1[j] * alpha + x1;
    }
  }
  // reduce 4 k-subsets, write
  for (int j = 0; j < 8; ++j) {
    int q = qbase + wave * 8 + j;
    if (q >= NQ) continue;
    float x0 = a0[j], x1 = a1[j];
    x0 += __shfl_xor(x0, 16); x0 += __shfl_xor(x0, 32);
    x1 += __shfl_xor(x1, 16); x1 += __shfl_xor(x1, 32);
    if (ks == 0) {
      float inv = 1.0f / l_run[j];
      size_t o = ((size_t)q * BB + b) * 256 + h * 32 + dp;
      sa[o] = x0 * inv;
      sa[o + 1] = x1 * inv;
    }
  }
}

// ---------------------------------------------------------------------------
// deformable sampling: block per (q,b) row r=q*8+b. Phase 1: 160 threads
// compute aw softmax + 4 taps per (h,l,p). Phase 2: thread (h,d) gathers 80
// bf16 taps and accumulates. out: ca_in[r*256 + h*32 + d].
// ---------------------------------------------------------------------------
__global__ __launch_bounds__(256) void deform_kernel(
    const bf16_t* __restrict__ value, const float* __restrict__ offs,
    const float* __restrict__ awl, const float* __restrict__ refp,
    float* __restrict__ out)
{
  __shared__ float logits[160];
  __shared__ float wfin[160][4];
  __shared__ int   tidx[160][4];
  __shared__ float hmax[8], hsum[8];
  const int r = blockIdx.x;         // q*8 + b
  const int b = r & 7;
  const int t = threadIdx.x;
  if (t < 160) {
    int i20 = t % 20;
    int l = i20 / 5;
    logits[t] = awl[(size_t)r * 160 + t];
    float ox = offs[(size_t)r * 320 + t * 2];
    float oy = offs[(size_t)r * 320 + t * 2 + 1];
    const float* rp = refp + ((size_t)r * LL + l) * 4;
    int Wl = 128 >> l;
    int st = (l == 0) ? 0 : (l == 1) ? 16384 : (l == 2) ? 20480 : 21504;
    float lx = rp[0] + ox * 0.1f * rp[2];   // offsets/P * ref[2:] * 0.5
    float ly = rp[1] + oy * 0.1f * rp[3];
    float xx = lx * (float)Wl - 0.5f;
    float yy = ly * (float)Wl - 0.5f;       // Hl == Wl (square levels)
    float x0f = floorf(xx), y0f = floorf(yy);
    float fx = xx - x0f, fy = yy - y0f;
    int x0 = (int)x0f, y0 = (int)y0f;
#pragma unroll
    for (int tap = 0; tap < 4; ++tap) {
      int dx = tap & 1, dy = tap >> 1;
      int xi = x0 + dx, yi = y0 + dy;
      float w = (dx ? fx : 1.0f - fx) * (dy ? fy : 1.0f - fy);
      bool valid = (xi >= 0) & (xi < Wl) & (yi >= 0) & (yi < Wl);
      int xc = min(max(xi, 0), Wl - 1);
      int yc = min(max(yi, 0), Wl - 1);
      tidx[t][tap] = (st + yc * Wl + xc) * BB + b;
      wfin[t][tap] = valid ? w : 0.0f;
    }
  }
  __syncthreads();
  if (t < 8) {
    float m = -1e30f;
    for (int i = 0; i < 20; ++i) m = fmaxf(m, logits[t * 20 + i]);
    float s = 0.f;
    for (int i = 0; i < 20; ++i) s += __expf(logits[t * 20 + i] - m);
    hmax[t] = m; hsum[t] = s;
  }
  __syncthreads();
  if (t < 160) {
    int h = t / 20;
    float p = __expf(logits[t] - hmax[h]) / hsum[h];
#pragma unroll
    for (int tap = 0; tap < 4; ++tap) wfin[t][tap] *= p;
  }
  __syncthreads();
  const int h = t >> 5, d = t & 31;
  const bf16_t* vbase = value + h * 32 + d;
  float acc = 0.f;
#pragma unroll 4
  for (int i = 0; i < 20; ++i) {
    int e = h * 20 + i;
#pragma unroll
    for (int tap = 0; tap < 4; ++tap) {
      float w = wfin[e][tap];
      float v = (float)vbase[(size_t)tidx[e][tap] * 256];
      acc = fmaf(w, v, acc);
    }
  }
  out[(size_t)r * 256 + t] = acc;
}

// ---------------------------------------------------------------------------
// launch
// ---------------------------------------------------------------------------
static inline dim3 gemm_grid(int M, int N) {
  return dim3(((M + 63) / 64) * ((N + 63) / 64));
}

extern "C" void kernel_launch(void* const* d_in, const int* in_sizes, int n_in,
                              void* d_out, int out_size, void* d_ws, size_t ws_size,
                              hipStream_t stream) {
  const float* tgt     = (const float*)d_in[0];
  const float* pos     = (const float*)d_in[1];
  const float* refp    = (const float*)d_in[2];
  const float* memory  = (const float*)d_in[3];
  const float* sa_in_w = (const float*)d_in[4];
  const float* sa_in_b = (const float*)d_in[5];
  const float* sa_out_w= (const float*)d_in[6];
  const float* sa_out_b= (const float*)d_in[7];
  const float* off_w   = (const float*)d_in[8];
  const float* off_b   = (const float*)d_in[9];
  const float* aw_w    = (const float*)d_in[10];
  const float* aw_b    = (const float*)d_in[11];
  const float* val_w   = (const float*)d_in[12];
  const float* val_b   = (const float*)d_in[13];
  const float* co_w    = (const float*)d_in[14];
  const float* co_b    = (const float*)d_in[15];
  const float* w1      = (const float*)d_in[16];
  const float* b1      = (const float*)d_in[17];
  const float* w2      = (const float*)d_in[18];
  const float* b2      = (const float*)d_in[19];
  const float* ln1_g   = (const float*)d_in[20];
  const float* ln1_b   = (const float*)d_in[21];
  const float* ln2_g   = (const float*)d_in[22];
  const float* ln2_b   = (const float*)d_in[23];
  const float* ln3_g   = (const float*)d_in[24];
  const float* ln3_b   = (const float*)d_in[25];

  char* ws = (char*)d_ws;
  // ws layout (bytes), with phase-based reuse; peak = 169,308,160 B
  bf16_t* value  = (bf16_t*)ws;                          // 89,128,960 (bf16 [S*B,256])
  float*  qk     = (float*)(ws + 89128960);              // 14,745,600 ([7200,512]) | ffn1 29,491,200
  float*  ffn1   = qk;                                   // [7200,1024] (phase C)
  float*  tgt2   = (float*)(ws + 118620160);             // 7,372,800
  float*  query  = (float*)(ws + 125992960);             // 7,372,800  | ffn2 (phase C)
  float*  ffn2   = query;
  float*  offs   = (float*)(ws + 133365760);             // 9,216,000  ([7200,320])
  float*  awl    = (float*)(ws + 142581760);             // 4,608,000  ([7200,160])
  float*  vp_buf = (float*)(ws + 147189760);             // 7,372,800  vp | sa_out tmp | ca_in
  float*  sa_buf = (float*)(ws + 154562560);             // 7,372,800  sa | ca
  float*  qsum   = (float*)(ws + 161935360);             // 7,372,800  q_sum | tgt3
  float*  tgt3   = qsum;
  float*  outp   = (float*)d_out;

  const int n4 = MQ * DD / 4;  // 460800

  // ---- self-attention ----
  add_kernel<<<dim3((n4 + 255) / 256), 256, 0, stream>>>(
      (const float4*)tgt, (const float4*)pos, (float4*)qsum, n4);
  gemm_bt<0, float><<<gemm_grid(MQ, 512), 256, 0, stream>>>(
      qsum, sa_in_w, sa_in_b, qk, MQ, 512, 256);
  gemm_bt<0, float><<<gemm_grid(MQ, 256), 256, 0, stream>>>(
      tgt, sa_in_w + 512 * 256, sa_in_b + 512, vp_buf, MQ, 256, 256);
  attn_kernel<<<dim3(64, (NQ + 31) / 32), 256, 0, stream>>>(qk, vp_buf, sa_buf);
  gemm_bt<0, float><<<gemm_grid(MQ, 256), 256, 0, stream>>>(
      sa_buf, sa_out_w, sa_out_b, vp_buf, MQ, 256, 256);   // vp dead -> reuse as tmp
  lnres_kernel<<<dim3((MQ + 3) / 4), 256, 0, stream>>>(
      vp_buf, tgt, ln2_g, ln2_b, tgt2, MQ);

  // ---- deformable cross-attention ----
  add_kernel<<<dim3((n4 + 255) / 256), 256, 0, stream>>>(
      (const float4*)tgt2, (const float4*)pos, (float4*)query, n4);
  gemm_bt<0, bf16_t><<<gemm_grid(MV, 256), 256, 0, stream>>>(
      memory, val_w, val_b, value, MV, 256, 256);
  gemm_bt<0, float><<<gemm_grid(MQ, 320), 256, 0, stream>>>(
      query, off_w, off_b, offs, MQ, 320, 256);
  gemm_bt<0, float><<<gemm_grid(MQ, 160), 256, 0, stream>>>(
      query, aw_w, aw_b, awl, MQ, 160, 256);
  deform_kernel<<<dim3(MQ), 256, 0, stream>>>(value, offs, awl, refp, vp_buf); // ca_in
  gemm_bt<0, float><<<gemm_grid(MQ, 256), 256, 0, stream>>>(
      vp_buf, co_w, co_b, sa_buf, MQ, 256, 256);           // ca
  lnres_kernel<<<dim3((MQ + 3) / 4), 256, 0, stream>>>(
      sa_buf, tgt2, ln1_g, ln1_b, tgt3, MQ);

  // ---- FFN ----
  gemm_bt<1, float><<<gemm_grid(MQ, DFF), 256, 0, stream>>>(
      tgt3, w1, b1, ffn1, MQ, DFF, 256);
  gemm_bt<0, float><<<gemm_grid(MQ, 256), 256, 0, stream>>>(
      ffn1, w2, b2, ffn2, MQ, 256, DFF);
  lnres_kernel<<<dim3((MQ + 3) / 4), 256, 0, stream>>>(
      ffn2, tgt3, ln3_g, ln3_b, outp, MQ);

  (void)in_sizes; (void)n_in; (void)out_size; (void)ws_size;
}

// Round 2
// 1052.340 us; speedup vs baseline: 1.8321x; 1.8321x over previous
//
#include <hip/hip_runtime.h>
#include <hip/hip_bf16.h>

#define NQ   900
#define BB   8
#define DD   256
#define HH   8
#define DH   32
#define LL   4
#define PP   5
#define SS   21760
#define DFF  1024
#define MQ   (NQ*BB)      // 7200
#define MV   (SS*BB)      // 174080

typedef __bf16 bf16_t;
typedef __bf16 bf16x8 __attribute__((ext_vector_type(8)));
typedef __bf16 bf16x4 __attribute__((ext_vector_type(4)));
typedef float  f32x4  __attribute__((ext_vector_type(4)));

// async global->LDS 16B copy (wave-uniform LDS base + lane*16 layout required)
__device__ __forceinline__ void async16(const void* g, void* l) {
  __builtin_amdgcn_global_load_lds(
      (const __attribute__((address_space(1))) unsigned int*)g,
      (__attribute__((address_space(3))) unsigned int*)l, 16, 0, 0);
}

// ---------------------------------------------------------------------------
// m97-style GEMM: C[M,N] = A[M,K] @ W[N,K]^T + bias.  128x128 tile, BK=32,
// 256 thr = 4 waves (2x2), each wave 64x64 via 4x4 mfma_f32_16x16x32_bf16.
// W is bf16 (pre-converted). A is f32 or bf16 (template). XOR chunk swizzle
// keeps frag ds_read_b128 at <=2-way bank aliasing (free, m136) while staying
// contiguous for global_load_lds (no padding allowed, m104/m108).
// ---------------------------------------------------------------------------
template<typename AT, int EPI, typename OT>
__global__ __launch_bounds__(256) void gemm128(
    const AT* __restrict__ A, const bf16_t* __restrict__ W,
    const float* __restrict__ bias, OT* __restrict__ C,
    int M, int N, int K, int tiles_n)
{
  constexpr bool AF = (sizeof(AT) == 4);
  __shared__ __align__(16) AT     As[128 * 32];
  __shared__ __align__(16) bf16_t Bs[128 * 32];
  const int tm = blockIdx.x / tiles_n;
  const int tn = blockIdx.x - tm * tiles_n;
  const int m0 = tm << 7, n0 = tn << 7;
  const int t = threadIdx.x;
  const int wave = t >> 6, lane = t & 63;
  const int wr = wave >> 1, wc = wave & 1;
  const int lm = lane & 15, kq = lane >> 4;

  f32x4 acc[4][4];
#pragma unroll
  for (int i = 0; i < 4; ++i)
#pragma unroll
    for (int j = 0; j < 4; ++j) acc[i][j] = (f32x4){0.f, 0.f, 0.f, 0.f};

  for (int k0 = 0; k0 < K; k0 += 32) {
    __syncthreads();
    // ---- A staging ----
    if constexpr (AF) {
#pragma unroll
      for (int i = 0; i < 4; ++i) {
        int flat = i * 4096 + t * 16;            // byte offset in As
        int row = flat >> 7;                     // 128 B per row (32 f32)
        int cl = (flat >> 4) & 7;
        int cg = cl ^ (row & 7);
        int grow = m0 + row; if (grow >= M) grow = M - 1;
        async16(&A[(size_t)grow * K + k0 + cg * 4], (char*)As + flat);
      }
    } else {
#pragma unroll
      for (int i = 0; i < 2; ++i) {
        int flat = i * 4096 + t * 16;            // 64 B per row (32 bf16)
        int row = flat >> 6;
        int cl = (flat >> 4) & 3;
        int cg = cl ^ ((row >> 1) & 3);
        int grow = m0 + row; if (grow >= M) grow = M - 1;
        async16(&A[(size_t)grow * K + k0 + cg * 8], (char*)As + flat);
      }
    }
    // ---- B staging (bf16) ----
#pragma unroll
    for (int i = 0; i < 2; ++i) {
      int flat = i * 4096 + t * 16;
      int row = flat >> 6;
      int cl = (flat >> 4) & 3;
      int cg = cl ^ ((row >> 1) & 3);
      int grow = n0 + row; if (grow >= N) grow = N - 1;
      async16(&W[(size_t)grow * K + k0 + cg * 8], (char*)Bs + flat);
    }
    __syncthreads();   // drains vmcnt before barrier -> LDS ready

    bf16x8 af[4], bfr[4];
#pragma unroll
    for (int mi = 0; mi < 4; ++mi) {
      int row = wr * 64 + mi * 16 + lm;
      if constexpr (AF) {
        int s = row & 7;
        const float* rp = (const float*)As + row * 32;
        f32x4 lo = *(const f32x4*)(rp + (((2 * kq) ^ s) << 2));
        f32x4 hi = *(const f32x4*)(rp + (((2 * kq + 1) ^ s) << 2));
        bf16x8 f;
#pragma unroll
        for (int j = 0; j < 4; ++j) { f[j] = (bf16_t)lo[j]; f[4 + j] = (bf16_t)hi[j]; }
        af[mi] = f;
      } else {
        int s = (row >> 1) & 3;
        af[mi] = *(const bf16x8*)((const bf16_t*)As + row * 32 + ((kq ^ s) << 3));
      }
    }
#pragma unroll
    for (int ni = 0; ni < 4; ++ni) {
      int row = wc * 64 + ni * 16 + lm;
      int s = (row >> 1) & 3;
      bfr[ni] = *(const bf16x8*)(Bs + row * 32 + ((kq ^ s) << 3));
    }
#pragma unroll
    for (int mi = 0; mi < 4; ++mi)
#pragma unroll
      for (int ni = 0; ni < 4; ++ni)
        acc[mi][ni] = __builtin_amdgcn_mfma_f32_16x16x32_bf16(af[mi], bfr[ni], acc[mi][ni], 0, 0, 0);
  }

  // epilogue: C/D layout col=lane&15, row=(lane>>4)*4+reg  [m89-verified]
  const int colb = n0 + wc * 64 + lm;
  float bv[4]; bool cok[4];
#pragma unroll
  for (int ni = 0; ni < 4; ++ni) {
    int c = colb + ni * 16;
    cok[ni] = (c < N);
    bv[ni] = cok[ni] ? bias[c] : 0.f;
  }
#pragma unroll
  for (int mi = 0; mi < 4; ++mi) {
    int rbase = m0 + wr * 64 + mi * 16 + kq * 4;
#pragma unroll
    for (int reg = 0; reg < 4; ++reg) {
      int r = rbase + reg;
      if (r < M) {
#pragma unroll
        for (int ni = 0; ni < 4; ++ni) if (cok[ni]) {
          float v = acc[mi][ni][reg] + bv[ni];
          if (EPI == 1) v = fmaxf(v, 0.f);
          C[(size_t)r * N + colb + ni * 16] = (OT)v;
        }
      }
    }
  }
}

// ---------------------------------------------------------------------------
// f32 -> bf16 convert (8 elems/thread)
// ---------------------------------------------------------------------------
__global__ __launch_bounds__(256) void cvt_kernel(
    const float* __restrict__ in, bf16_t* __restrict__ out, int n8)
{
  int i = blockIdx.x * 256 + threadIdx.x;
  if (i < n8) {
    f32x4 x0 = ((const f32x4*)in)[2 * i], x1 = ((const f32x4*)in)[2 * i + 1];
    bf16x8 r;
#pragma unroll
    for (int j = 0; j < 4; ++j) { r[j] = (bf16_t)x0[j]; r[4 + j] = (bf16_t)x1[j]; }
    ((bf16x8*)out)[i] = r;
  }
}

// a + b (f32) -> bf16, 8 elems/thread
__global__ __launch_bounds__(256) void addpos_kernel(
    const float* __restrict__ a, const float* __restrict__ b,
    bf16_t* __restrict__ o, int n8)
{
  int i = blockIdx.x * 256 + threadIdx.x;
  if (i < n8) {
    f32x4 x0 = ((const f32x4*)a)[2 * i], x1 = ((const f32x4*)a)[2 * i + 1];
    f32x4 y0 = ((const f32x4*)b)[2 * i], y1 = ((const f32x4*)b)[2 * i + 1];
    bf16x8 r;
#pragma unroll
    for (int j = 0; j < 4; ++j) { r[j] = (bf16_t)(x0[j] + y0[j]); r[4 + j] = (bf16_t)(x1[j] + y1[j]); }
    ((bf16x8*)o)[i] = r;
  }
}

// ---------------------------------------------------------------------------
// residual + layernorm (f32 out, optional bf16 second output), D=256
// ---------------------------------------------------------------------------
template<int WBF>
__global__ __launch_bounds__(256) void lnres_kernel(
    const float* __restrict__ x, const float* __restrict__ res,
    const float* __restrict__ g, const float* __restrict__ bta,
    float* __restrict__ out, bf16_t* __restrict__ outb, int rows)
{
  int wave = threadIdx.x >> 6, lane = threadIdx.x & 63;
  int row = blockIdx.x * 4 + wave;
  if (row >= rows) return;
  const float4* xp = (const float4*)(x + (size_t)row * DD);
  const float4* rp = (const float4*)(res + (size_t)row * DD);
  float4 v = xp[lane], rr = rp[lane];
  float a0 = v.x + rr.x, a1 = v.y + rr.y, a2 = v.z + rr.z, a3 = v.w + rr.w;
  float s = a0 + a1 + a2 + a3;
#pragma unroll
  for (int off = 32; off; off >>= 1) s += __shfl_xor(s, off);
  float mean = s * (1.0f / DD);
  float d0 = a0 - mean, d1 = a1 - mean, d2 = a2 - mean, d3 = a3 - mean;
  float vs = d0 * d0 + d1 * d1 + d2 * d2 + d3 * d3;
#pragma unroll
  for (int off = 32; off; off >>= 1) vs += __shfl_xor(vs, off);
  float inv = rsqrtf(vs * (1.0f / DD) + 1e-5f);
  float4 gg = ((const float4*)g)[lane];
  float4 bb = ((const float4*)bta)[lane];
  float o0 = d0 * inv * gg.x + bb.x, o1 = d1 * inv * gg.y + bb.y;
  float o2 = d2 * inv * gg.z + bb.z, o3 = d3 * inv * gg.w + bb.w;
  float4 o; o.x = o0; o.y = o1; o.z = o2; o.w = o3;
  ((float4*)(out + (size_t)row * DD))[lane] = o;
  if (WBF) {
    bf16x4 ob; ob[0] = (bf16_t)o0; ob[1] = (bf16_t)o1; ob[2] = (bf16_t)o2; ob[3] = (bf16_t)o3;
    ((bf16x4*)(outb + (size_t)row * DD))[lane] = ob;
  }
}

// ---------------------------------------------------------------------------
// fused self-attention, bf16 q/k/v in LDS, online softmax. qk: bf16 [7200,512]
// (q|k), vp: bf16 [7200,256], sa out bf16 [7200,256].
// ---------------------------------------------------------------------------
#define CK 225
__device__ __forceinline__ void bf2x(unsigned u, float& lo, float& hi) {
  lo = __uint_as_float(u << 16);
  hi = __uint_as_float(u & 0xffff0000u);
}

__global__ __launch_bounds__(256) void attn_kernel(
    const bf16_t* __restrict__ qk, const bf16_t* __restrict__ vp,
    bf16_t* __restrict__ sa)
{
  __shared__ __align__(16) bf16_t Kt[CK * 32];
  __shared__ __align__(16) bf16_t Vt[CK * 32];
  __shared__ float sbuf[4][CK];
  const int bh = blockIdx.x;
  const int b = bh & 7, h = bh >> 3;
  const int qbase = blockIdx.y * 32;
  const int t = threadIdx.x, wave = t >> 6, lane = t & 63;
  const int dp = (lane & 15) * 2;
  const int ks = lane >> 4;
  const float scale = 0.17677669529663687f;  // 1/sqrt(32)

  float m_run[8], l_run[8], a0[8], a1[8];
#pragma unroll
  for (int j = 0; j < 8; ++j) { m_run[j] = -1e30f; l_run[j] = 0.f; a0[j] = 0.f; a1[j] = 0.f; }

  for (int c = 0; c < 4; ++c) {
    const int k0 = c * CK;
    __syncthreads();
    for (int idx = t; idx < CK * 4; idx += 256) {   // 8 bf16 per chunk
      int row = idx >> 2, c8 = idx & 3;
      *(bf16x8*)&Kt[row * 32 + c8 * 8] =
          *(const bf16x8*)&qk[((size_t)(k0 + row) * BB + b) * 512 + 256 + h * 32 + c8 * 8];
      *(bf16x8*)&Vt[row * 32 + c8 * 8] =
          *(const bf16x8*)&vp[((size_t)(k0 + row) * BB + b) * 256 + h * 32 + c8 * 8];
    }
    __syncthreads();
    for (int j = 0; j < 8; ++j) {
      int q = qbase + wave * 8 + j;
      if (q >= NQ) continue;
      float qv[32];
      const bf16_t* qptr = qk + ((size_t)q * BB + b) * 512 + h * 32;
#pragma unroll
      for (int c8 = 0; c8 < 4; ++c8) {
        bf16x8 qq = *(const bf16x8*)(qptr + c8 * 8);
#pragma unroll
        for (int u = 0; u < 8; ++u) qv[c8 * 8 + u] = (float)qq[u];
      }
      float sarr[4];
      float lmax = -1e30f;
#pragma unroll
      for (int i = 0; i < 4; ++i) {
        int k = lane + i * 64;
        float sv = -1e30f;
        if (k < CK) {
          const uint4* kr = (const uint4*)&Kt[k * 32];
          float acc = 0.f;
#pragma unroll
          for (int c8 = 0; c8 < 4; ++c8) {
            uint4 kvv = kr[c8];
            float l0, h0, l1, h1, l2, h2, l3, h3;
            bf2x(kvv.x, l0, h0); bf2x(kvv.y, l1, h1);
            bf2x(kvv.z, l2, h2); bf2x(kvv.w, l3, h3);
            int dd = c8 * 8;
            acc = fmaf(qv[dd + 0], l0, acc); acc = fmaf(qv[dd + 1], h0, acc);
            acc = fmaf(qv[dd + 2], l1, acc); acc = fmaf(qv[dd + 3], h1, acc);
            acc = fmaf(qv[dd + 4], l2, acc); acc = fmaf(qv[dd + 5], h2, acc);
            acc = fmaf(qv[dd + 6], l3, acc); acc = fmaf(qv[dd + 7], h3, acc);
          }
          sv = acc * scale;
        }
        sarr[i] = sv;
        lmax = fmaxf(lmax, sv);
      }
#pragma unroll
      for (int off = 32; off; off >>= 1) lmax = fmaxf(lmax, __shfl_xor(lmax, off));
      float m_new = fmaxf(m_run[j], lmax);
      float alpha = __expf(m_run[j] - m_new);
      float psum = 0.f;
#pragma unroll
      for (int i = 0; i < 4; ++i) {
        int k = lane + i * 64;
        if (k < CK) {
          float p = __expf(sarr[i] - m_new);
          sbuf[wave][k] = p;
          psum += p;
        }
      }
#pragma unroll
      for (int off = 32; off; off >>= 1) psum += __shfl_xor(psum, off);
      l_run[j] = l_run[j] * alpha + psum;
      m_run[j] = m_new;
      float x0 = 0.f, x1 = 0.f;
      for (int k = ks; k < CK; k += 4) {
        float p = sbuf[wave][k];
        unsigned vv = *(const unsigned*)&Vt[k * 32 + dp];
        float v0, v1; bf2x(vv, v0, v1);
        x0 = fmaf(p, v0, x0);
        x1 = fmaf(p, v1, x1);
      }
      a0[j] = a0[j] * alpha + x0;
      a1[j] = a1[j] * alpha + x1;
    }
  }
  for (int j = 0; j < 8; ++j) {
    int q = qbase + wave * 8 + j;
    if (q >= NQ) continue;
    float x0 = a0[j], x1 = a1[j];
    x0 += __shfl_xor(x0, 16); x0 += __shfl_xor(x0, 32);
    x1 += __shfl_xor(x1, 16); x1 += __shfl_xor(x1, 32);
    if (ks == 0) {
      float inv = 1.0f / l_run[j];
      size_t o = ((size_t)q * BB + b) * 256 + h * 32 + dp;
      sa[o] = (bf16_t)(x0 * inv);
      sa[o + 1] = (bf16_t)(x1 * inv);
    }
  }
}

// ---------------------------------------------------------------------------
// deformable sampling: block per row r=q*8+b; out bf16 [7200,256]
// ---------------------------------------------------------------------------
__global__ __launch_bounds__(256) void deform_kernel(
    const bf16_t* __restrict__ value, const float* __restrict__ offs,
    const float* __restrict__ awl, const float* __restrict__ refp,
    bf16_t* __restrict__ out)
{
  __shared__ float logits[160];
  __shared__ float wfin[160][4];
  __shared__ int   tidx[160][4];
  __shared__ float hmax[8], hsum[8];
  const int r = blockIdx.x;
  const int b = r & 7;
  const int t = threadIdx.x;
  if (t < 160) {
    int i20 = t % 20;
    int l = i20 / 5;
    logits[t] = awl[(size_t)r * 160 + t];
    float ox = offs[(size_t)r * 320 + t * 2];
    float oy = offs[(size_t)r * 320 + t * 2 + 1];
    const float* rp = refp + ((size_t)r * LL + l) * 4;
    int Wl = 128 >> l;
    int st = (l == 0) ? 0 : (l == 1) ? 16384 : (l == 2) ? 20480 : 21504;
    float lx = rp[0] + ox * 0.1f * rp[2];
    float ly = rp[1] + oy * 0.1f * rp[3];
    float xx = lx * (float)Wl - 0.5f;
    float yy = ly * (float)Wl - 0.5f;
    float x0f = floorf(xx), y0f = floorf(yy);
    float fx = xx - x0f, fy = yy - y0f;
    int x0 = (int)x0f, y0 = (int)y0f;
#pragma unroll
    for (int tap = 0; tap < 4; ++tap) {
      int dx = tap & 1, dy = tap >> 1;
      int xi = x0 + dx, yi = y0 + dy;
      float w = (dx ? fx : 1.0f - fx) * (dy ? fy : 1.0f - fy);
      bool valid = (xi >= 0) & (xi < Wl) & (yi >= 0) & (yi < Wl);
      int xc = min(max(xi, 0), Wl - 1);
      int yc = min(max(yi, 0), Wl - 1);
      tidx[t][tap] = (st + yc * Wl + xc) * BB + b;
      wfin[t][tap] = valid ? w : 0.0f;
    }
  }
  __syncthreads();
  if (t < 8) {
    float m = -1e30f;
    for (int i = 0; i < 20; ++i) m = fmaxf(m, logits[t * 20 + i]);
    float s = 0.f;
    for (int i = 0; i < 20; ++i) s += __expf(logits[t * 20 + i] - m);
    hmax[t] = m; hsum[t] = s;
  }
  __syncthreads();
  if (t < 160) {
    int h = t / 20;
    float p = __expf(logits[t] - hmax[h]) / hsum[h];
#pragma unroll
    for (int tap = 0; tap < 4; ++tap) wfin[t][tap] *= p;
  }
  __syncthreads();
  const int h = t >> 5, d = t & 31;
  const bf16_t* vbase = value + h * 32 + d;
  float acc = 0.f;
#pragma unroll 4
  for (int i = 0; i < 20; ++i) {
    int e = h * 20 + i;
#pragma unroll
    for (int tap = 0; tap < 4; ++tap) {
      float w = wfin[e][tap];
      float v = (float)vbase[(size_t)tidx[e][tap] * 256];
      acc = fmaf(w, v, acc);
    }
  }
  out[(size_t)r * 256 + t] = (bf16_t)acc;
}

// ---------------------------------------------------------------------------
// launch
// ---------------------------------------------------------------------------
static inline int tiles(int x) { return (x + 127) >> 7; }

extern "C" void kernel_launch(void* const* d_in, const int* in_sizes, int n_in,
                              void* d_out, int out_size, void* d_ws, size_t ws_size,
                              hipStream_t stream) {
  const float* tgt     = (const float*)d_in[0];
  const float* pos     = (const float*)d_in[1];
  const float* refp    = (const float*)d_in[2];
  const float* memory  = (const float*)d_in[3];
  const float* sa_in_w = (const float*)d_in[4];
  const float* sa_in_b = (const float*)d_in[5];
  const float* sa_out_w= (const float*)d_in[6];
  const float* sa_out_b= (const float*)d_in[7];
  const float* off_w   = (const float*)d_in[8];
  const float* off_b   = (const float*)d_in[9];
  const float* aw_w    = (const float*)d_in[10];
  const float* aw_b    = (const float*)d_in[11];
  const float* val_w   = (const float*)d_in[12];
  const float* val_b   = (const float*)d_in[13];
  const float* co_w    = (const float*)d_in[14];
  const float* co_b    = (const float*)d_in[15];
  const float* w1      = (const float*)d_in[16];
  const float* b1      = (const float*)d_in[17];
  const float* w2      = (const float*)d_in[18];
  const float* b2      = (const float*)d_in[19];
  const float* ln1_g   = (const float*)d_in[20];
  const float* ln1_b   = (const float*)d_in[21];
  const float* ln2_g   = (const float*)d_in[22];
  const float* ln2_b   = (const float*)d_in[23];
  const float* ln3_g   = (const float*)d_in[24];
  const float* ln3_b   = (const float*)d_in[25];

  char* ws = (char*)d_ws;
  // ws layout (bytes), 164,016,128 total (<169.3MB proven available)
  bf16_t* value_bf = (bf16_t*)ws;                        // 89,128,960
  bf16_t* qk_bf    = (bf16_t*)(ws + 89128960);           // 7,372,800 | h1_bf 14,745,600 (qk dead by FFN)
  bf16_t* h1_bf    = qk_bf;
  bf16_t* qsum_bf  = (bf16_t*)(ws + 103874560);          // 3,686,400
  bf16_t* vp_bf    = (bf16_t*)(ws + 107560960);          // 3,686,400
  bf16_t* sa_bf    = (bf16_t*)(ws + 111247360);          // 3,686,400
  float*  tgt2     = (float*)(ws + 114933760);           // 7,372,800
  bf16_t* query_bf = (bf16_t*)(ws + 122306560);          // 3,686,400
  float*  offs     = (float*)(ws + 125992960);           // 9,216,000
  float*  awl      = (float*)(ws + 135208960);           // 4,608,000
  bf16_t* ca_bf    = (bf16_t*)(ws + 139816960);          // 3,686,400
  float*  gout     = (float*)(ws + 143503360);           // 7,372,800 (saout|ca|ffn2)
  float*  tgt3     = (float*)(ws + 150876160);           // 7,372,800
  bf16_t* tgt3_bf  = (bf16_t*)(ws + 158248960);          // 3,686,400
  bf16_t* wbf      = (bf16_t*)(ws + 161935360);          // 2,080,768
  bf16_t* sa_in_wb = wbf;                                // 196,608 elems
  bf16_t* sa_out_wb= wbf + 196608;                       // 65,536
  bf16_t* off_wb   = wbf + 262144;                       // 81,920
  bf16_t* aw_wb    = wbf + 344064;                       // 40,960
  bf16_t* val_wb   = wbf + 385024;                       // 65,536
  bf16_t* co_wb    = wbf + 450560;                       // 65,536
  bf16_t* w1b      = wbf + 516096;                       // 262,144
  bf16_t* w2b      = wbf + 778240;                       // 262,144
  float*  outp     = (float*)d_out;

  const int n8q = MQ * DD / 8;  // 230400

  // ---- weight converts (bf16) ----
  auto cvt = [&](const float* in, bf16_t* out, int n) {
    int n8 = n / 8;
    cvt_kernel<<<dim3((n8 + 255) / 256), 256, 0, stream>>>(in, out, n8);
  };
  cvt(sa_in_w, sa_in_wb, 196608);
  cvt(sa_out_w, sa_out_wb, 65536);
  cvt(off_w, off_wb, 81920);
  cvt(aw_w, aw_wb, 40960);
  cvt(val_w, val_wb, 65536);
  cvt(co_w, co_wb, 65536);
  cvt(w1, w1b, 262144);
  cvt(w2, w2b, 262144);

  // ---- self-attention ----
  addpos_kernel<<<dim3((n8q + 255) / 256), 256, 0, stream>>>(tgt, pos, qsum_bf, n8q);
  gemm128<bf16_t, 0, bf16_t><<<dim3(tiles(MQ) * 4), 256, 0, stream>>>(
      qsum_bf, sa_in_wb, sa_in_b, qk_bf, MQ, 512, 256, 4);
  gemm128<float, 0, bf16_t><<<dim3(tiles(MQ) * 2), 256, 0, stream>>>(
      tgt, sa_in_wb + 512 * 256, sa_in_b + 512, vp_bf, MQ, 256, 256, 2);
  attn_kernel<<<dim3(64, (NQ + 31) / 32), 256, 0, stream>>>(qk_bf, vp_bf, sa_bf);
  gemm128<bf16_t, 0, float><<<dim3(tiles(MQ) * 2), 256, 0, stream>>>(
      sa_bf, sa_out_wb, sa_out_b, gout, MQ, 256, 256, 2);
  lnres_kernel<0><<<dim3((MQ + 3) / 4), 256, 0, stream>>>(
      gout, tgt, ln2_g, ln2_b, tgt2, (bf16_t*)nullptr, MQ);

  // ---- deformable cross-attention ----
  addpos_kernel<<<dim3((n8q + 255) / 256), 256, 0, stream>>>(tgt2, pos, query_bf, n8q);
  gemm128<float, 0, bf16_t><<<dim3(tiles(MV) * 2), 256, 0, stream>>>(
      memory, val_wb, val_b, value_bf, MV, 256, 256, 2);
  gemm128<bf16_t, 0, float><<<dim3(tiles(MQ) * 3), 256, 0, stream>>>(
      query_bf, off_wb, off_b, offs, MQ, 320, 256, 3);
  gemm128<bf16_t, 0, float><<<dim3(tiles(MQ) * 2), 256, 0, stream>>>(
      query_bf, aw_wb, aw_b, awl, MQ, 160, 256, 2);
  deform_kernel<<<dim3(MQ), 256, 0, stream>>>(value_bf, offs, awl, refp, ca_bf);
  gemm128<bf16_t, 0, float><<<dim3(tiles(MQ) * 2), 256, 0, stream>>>(
      ca_bf, co_wb, co_b, gout, MQ, 256, 256, 2);
  lnres_kernel<1><<<dim3((MQ + 3) / 4), 256, 0, stream>>>(
      gout, tgt2, ln1_g, ln1_b, tgt3, tgt3_bf, MQ);

  // ---- FFN ----
  gemm128<bf16_t, 1, bf16_t><<<dim3(tiles(MQ) * 8), 256, 0, stream>>>(
      tgt3_bf, w1b, b1, h1_bf, MQ, DFF, 256, 8);
  gemm128<bf16_t, 0, float><<<dim3(tiles(MQ) * 2), 256, 0, stream>>>(
      h1_bf, w2b, b2, gout, MQ, 256, DFF, 2);
  lnres_kernel<0><<<dim3((MQ + 3) / 4), 256, 0, stream>>>(
      gout, tgt3, ln3_g, ln3_b, outp, (bf16_t*)nullptr, MQ);

  (void)in_sizes; (void)n_in; (void)out_size; (void)ws_size;
}

// Round 3
// 629.337 us; speedup vs baseline: 3.0636x; 1.6721x over previous
//
#include <hip/hip_runtime.h>
#include <hip/hip_bf16.h>

#define NQ   900
#define BB   8
#define DD   256
#define HH   8
#define DH   32
#define LL   4
#define PP   5
#define SS   21760
#define DFF  1024
#define MQ   (NQ*BB)      // 7200
#define MV   (SS*BB)      // 174080

typedef __bf16 bf16_t;
typedef __bf16 bf16x8 __attribute__((ext_vector_type(8)));
typedef __bf16 bf16x4 __attribute__((ext_vector_type(4)));
typedef float  f32x4  __attribute__((ext_vector_type(4)));

// async global->LDS 16B copy (wave-uniform LDS base + lane*16 layout required)
__device__ __forceinline__ void async16(const void* g, void* l) {
  __builtin_amdgcn_global_load_lds(
      (const __attribute__((address_space(1))) unsigned int*)g,
      (__attribute__((address_space(3))) unsigned int*)l, 16, 0, 0);
}

// ---------------------------------------------------------------------------
// m97-style GEMM: C[M,N] = A[M,K] @ W[N,K]^T + bias.  128x128 tile, BK=32,
// 256 thr = 4 waves (2x2), each wave 64x64 via 4x4 mfma_f32_16x16x32_bf16.
// ---------------------------------------------------------------------------
template<typename AT, int EPI, typename OT>
__global__ __launch_bounds__(256) void gemm128(
    const AT* __restrict__ A, const bf16_t* __restrict__ W,
    const float* __restrict__ bias, OT* __restrict__ C,
    int M, int N, int K, int tiles_n)
{
  constexpr bool AF = (sizeof(AT) == 4);
  __shared__ __align__(16) AT     As[128 * 32];
  __shared__ __align__(16) bf16_t Bs[128 * 32];
  const int tm = blockIdx.x / tiles_n;
  const int tn = blockIdx.x - tm * tiles_n;
  const int m0 = tm << 7, n0 = tn << 7;
  const int t = threadIdx.x;
  const int wave = t >> 6, lane = t & 63;
  const int wr = wave >> 1, wc = wave & 1;
  const int lm = lane & 15, kq = lane >> 4;

  f32x4 acc[4][4];
#pragma unroll
  for (int i = 0; i < 4; ++i)
#pragma unroll
    for (int j = 0; j < 4; ++j) acc[i][j] = (f32x4){0.f, 0.f, 0.f, 0.f};

  for (int k0 = 0; k0 < K; k0 += 32) {
    __syncthreads();
    if constexpr (AF) {
#pragma unroll
      for (int i = 0; i < 4; ++i) {
        int flat = i * 4096 + t * 16;
        int row = flat >> 7;
        int cl = (flat >> 4) & 7;
        int cg = cl ^ (row & 7);
        int grow = m0 + row; if (grow >= M) grow = M - 1;
        async16(&A[(size_t)grow * K + k0 + cg * 4], (char*)As + flat);
      }
    } else {
#pragma unroll
      for (int i = 0; i < 2; ++i) {
        int flat = i * 4096 + t * 16;
        int row = flat >> 6;
        int cl = (flat >> 4) & 3;
        int cg = cl ^ ((row >> 1) & 3);
        int grow = m0 + row; if (grow >= M) grow = M - 1;
        async16(&A[(size_t)grow * K + k0 + cg * 8], (char*)As + flat);
      }
    }
#pragma unroll
    for (int i = 0; i < 2; ++i) {
      int flat = i * 4096 + t * 16;
      int row = flat >> 6;
      int cl = (flat >> 4) & 3;
      int cg = cl ^ ((row >> 1) & 3);
      int grow = n0 + row; if (grow >= N) grow = N - 1;
      async16(&W[(size_t)grow * K + k0 + cg * 8], (char*)Bs + flat);
    }
    __syncthreads();

    bf16x8 af[4], bfr[4];
#pragma unroll
    for (int mi = 0; mi < 4; ++mi) {
      int row = wr * 64 + mi * 16 + lm;
      if constexpr (AF) {
        int s = row & 7;
        const float* rp = (const float*)As + row * 32;
        f32x4 lo = *(const f32x4*)(rp + (((2 * kq) ^ s) << 2));
        f32x4 hi = *(const f32x4*)(rp + (((2 * kq + 1) ^ s) << 2));
        bf16x8 f;
#pragma unroll
        for (int j = 0; j < 4; ++j) { f[j] = (bf16_t)lo[j]; f[4 + j] = (bf16_t)hi[j]; }
        af[mi] = f;
      } else {
        int s = (row >> 1) & 3;
        af[mi] = *(const bf16x8*)((const bf16_t*)As + row * 32 + ((kq ^ s) << 3));
      }
    }
#pragma unroll
    for (int ni = 0; ni < 4; ++ni) {
      int row = wc * 64 + ni * 16 + lm;
      int s = (row >> 1) & 3;
      bfr[ni] = *(const bf16x8*)(Bs + row * 32 + ((kq ^ s) << 3));
    }
#pragma unroll
    for (int mi = 0; mi < 4; ++mi)
#pragma unroll
      for (int ni = 0; ni < 4; ++ni)
        acc[mi][ni] = __builtin_amdgcn_mfma_f32_16x16x32_bf16(af[mi], bfr[ni], acc[mi][ni], 0, 0, 0);
  }

  const int colb = n0 + wc * 64 + lm;
  float bv[4]; bool cok[4];
#pragma unroll
  for (int ni = 0; ni < 4; ++ni) {
    int c = colb + ni * 16;
    cok[ni] = (c < N);
    bv[ni] = cok[ni] ? bias[c] : 0.f;
  }
#pragma unroll
  for (int mi = 0; mi < 4; ++mi) {
    int rbase = m0 + wr * 64 + mi * 16 + kq * 4;
#pragma unroll
    for (int reg = 0; reg < 4; ++reg) {
      int r = rbase + reg;
      if (r < M) {
#pragma unroll
        for (int ni = 0; ni < 4; ++ni) if (cok[ni]) {
          float v = acc[mi][ni][reg] + bv[ni];
          if (EPI == 1) v = fmaxf(v, 0.f);
          C[(size_t)r * N + colb + ni * 16] = (OT)v;
        }
      }
    }
  }
}

// ---------------------------------------------------------------------------
// f32 -> bf16 convert (8 elems/thread)
// ---------------------------------------------------------------------------
__global__ __launch_bounds__(256) void cvt_kernel(
    const float* __restrict__ in, bf16_t* __restrict__ out, int n8)
{
  int i = blockIdx.x * 256 + threadIdx.x;
  if (i < n8) {
    f32x4 x0 = ((const f32x4*)in)[2 * i], x1 = ((const f32x4*)in)[2 * i + 1];
    bf16x8 r;
#pragma unroll
    for (int j = 0; j < 4; ++j) { r[j] = (bf16_t)x0[j]; r[4 + j] = (bf16_t)x1[j]; }
    ((bf16x8*)out)[i] = r;
  }
}

__global__ __launch_bounds__(256) void addpos_kernel(
    const float* __restrict__ a, const float* __restrict__ b,
    bf16_t* __restrict__ o, int n8)
{
  int i = blockIdx.x * 256 + threadIdx.x;
  if (i < n8) {
    f32x4 x0 = ((const f32x4*)a)[2 * i], x1 = ((const f32x4*)a)[2 * i + 1];
    f32x4 y0 = ((const f32x4*)b)[2 * i], y1 = ((const f32x4*)b)[2 * i + 1];
    bf16x8 r;
#pragma unroll
    for (int j = 0; j < 4; ++j) { r[j] = (bf16_t)(x0[j] + y0[j]); r[4 + j] = (bf16_t)(x1[j] + y1[j]); }
    ((bf16x8*)o)[i] = r;
  }
}

// ---------------------------------------------------------------------------
// residual + layernorm (f32 out, optional bf16 second output), D=256
// ---------------------------------------------------------------------------
template<int WBF>
__global__ __launch_bounds__(256) void lnres_kernel(
    const float* __restrict__ x, const float* __restrict__ res,
    const float* __restrict__ g, const float* __restrict__ bta,
    float* __restrict__ out, bf16_t* __restrict__ outb, int rows)
{
  int wave = threadIdx.x >> 6, lane = threadIdx.x & 63;
  int row = blockIdx.x * 4 + wave;
  if (row >= rows) return;
  const float4* xp = (const float4*)(x + (size_t)row * DD);
  const float4* rp = (const float4*)(res + (size_t)row * DD);
  float4 v = xp[lane], rr = rp[lane];
  float a0 = v.x + rr.x, a1 = v.y + rr.y, a2 = v.z + rr.z, a3 = v.w + rr.w;
  float s = a0 + a1 + a2 + a3;
#pragma unroll
  for (int off = 32; off; off >>= 1) s += __shfl_xor(s, off);
  float mean = s * (1.0f / DD);
  float d0 = a0 - mean, d1 = a1 - mean, d2 = a2 - mean, d3 = a3 - mean;
  float vs = d0 * d0 + d1 * d1 + d2 * d2 + d3 * d3;
#pragma unroll
  for (int off = 32; off; off >>= 1) vs += __shfl_xor(vs, off);
  float inv = rsqrtf(vs * (1.0f / DD) + 1e-5f);
  float4 gg = ((const float4*)g)[lane];
  float4 bb = ((const float4*)bta)[lane];
  float o0 = d0 * inv * gg.x + bb.x, o1 = d1 * inv * gg.y + bb.y;
  float o2 = d2 * inv * gg.z + bb.z, o3 = d3 * inv * gg.w + bb.w;
  float4 o; o.x = o0; o.y = o1; o.z = o2; o.w = o3;
  ((float4*)(out + (size_t)row * DD))[lane] = o;
  if (WBF) {
    bf16x4 ob; ob[0] = (bf16_t)o0; ob[1] = (bf16_t)o1; ob[2] = (bf16_t)o2; ob[3] = (bf16_t)o3;
    ((bf16x4*)(outb + (size_t)row * DD))[lane] = ob;
  }
}

// ---------------------------------------------------------------------------
// MFMA flash self-attention. Block = (b,h) x 64-q tile; 4 waves x 16 q rows.
// qk: bf16 [7200,512] (q|k), vp: bf16 [7200,256], sa: bf16 [7200,256].
// Per 128-key chunk: S=Q.K^T (8 mfma), online softmax in C-layout regs,
// P -> LDS (A-layout), PV with V^T staged in LDS (8 mfma).
// ---------------------------------------------------------------------------
__global__ __launch_bounds__(256) void attn_mfma(
    const bf16_t* __restrict__ qk, const bf16_t* __restrict__ vp,
    bf16_t* __restrict__ sa)
{
  __shared__ __align__(16) bf16_t Ks[128 * 32];       // swizzled chunks
  __shared__ __align__(16) bf16_t VT[32 * 136];       // [d][key] padded
  __shared__ __align__(16) bf16_t Pw[4][16 * 136];    // per-wave P [q][key]
  const int bh = blockIdx.x;
  const int b = bh & 7, h = bh >> 3;
  const int qt = blockIdx.y;
  const int t = threadIdx.x, wave = t >> 6, lane = t & 63;
  const int lm = lane & 15, quad = lane >> 4;
  const int q0 = qt * 64 + wave * 16;

  // Q A-frag (held in regs), pre-scaled by 1/sqrt(32)
  int qrow = q0 + lm; if (qrow > NQ - 1) qrow = NQ - 1;
  bf16x8 aqr = *(const bf16x8*)&qk[((size_t)qrow * BB + b) * 512 + h * 32 + quad * 8];
  bf16x8 aq;
#pragma unroll
  for (int j = 0; j < 8; ++j) aq[j] = (bf16_t)((float)aqr[j] * 0.17677669529663687f);

  f32x4 m_run = {-1e30f, -1e30f, -1e30f, -1e30f};
  f32x4 l_run = {0.f, 0.f, 0.f, 0.f};
  f32x4 o0 = {0.f, 0.f, 0.f, 0.f}, o1 = {0.f, 0.f, 0.f, 0.f};
  const f32x4 zero = {0.f, 0.f, 0.f, 0.f};

  for (int c = 0; c < 8; ++c) {
    const int k0 = c * 128;
    __syncthreads();
    // ---- stage K chunk via async16 (swizzled rows of 32 bf16) ----
#pragma unroll
    for (int i = 0; i < 2; ++i) {
      int flat = i * 4096 + t * 16;
      int row = flat >> 6;
      int cl = (flat >> 4) & 3;
      int cg = cl ^ ((row >> 1) & 3);
      int key = k0 + row; if (key > NQ - 1) key = NQ - 1;
      async16(&qk[((size_t)key * BB + b) * 512 + 256 + h * 32 + cg * 8], (char*)Ks + flat);
    }
    // ---- stage V^T (transpose through regs) ----
#pragma unroll
    for (int i = 0; i < 2; ++i) {
      int idx = t * 2 + i;            // 0..511
      int key = idx >> 2, dc = idx & 3;
      int gk = k0 + key;
      if (gk < NQ) {
        bf16x8 vv = *(const bf16x8*)&vp[((size_t)gk * BB + b) * 256 + h * 32 + dc * 8];
#pragma unroll
        for (int u = 0; u < 8; ++u) VT[(dc * 8 + u) * 136 + key] = vv[u];
      } else {
#pragma unroll
        for (int u = 0; u < 8; ++u) VT[(dc * 8 + u) * 136 + key] = (bf16_t)0.f;
      }
    }
    __syncthreads();

    // ---- S = Q K^T ----
    f32x4 s[8];
#pragma unroll
    for (int blk = 0; blk < 8; ++blk) {
      int row = blk * 16 + lm;
      int sw = (row >> 1) & 3;
      bf16x8 kb = *(const bf16x8*)&Ks[row * 32 + ((quad ^ sw) << 3)];
      s[blk] = __builtin_amdgcn_mfma_f32_16x16x32_bf16(aq, kb, zero, 0, 0, 0);
    }
    if (c == 7) {
#pragma unroll
      for (int blk = 0; blk < 8; ++blk) {
        if (k0 + blk * 16 + lm >= NQ) {
#pragma unroll
          for (int r = 0; r < 4; ++r) s[blk][r] = -1e30f;
        }
      }
    }
    // ---- row max ----
    f32x4 mx = s[0];
#pragma unroll
    for (int blk = 1; blk < 8; ++blk)
#pragma unroll
      for (int r = 0; r < 4; ++r) mx[r] = fmaxf(mx[r], s[blk][r]);
#pragma unroll
    for (int d = 1; d < 16; d <<= 1)
#pragma unroll
      for (int r = 0; r < 4; ++r) mx[r] = fmaxf(mx[r], __shfl_xor(mx[r], d));
    f32x4 m_new, alpha;
#pragma unroll
    for (int r = 0; r < 4; ++r) {
      m_new[r] = fmaxf(m_run[r], mx[r]);
      alpha[r] = __expf(m_run[r] - m_new[r]);
    }
    // ---- P = exp(S - m), write to LDS in A-layout ----
    f32x4 psum = {0.f, 0.f, 0.f, 0.f};
#pragma unroll
    for (int blk = 0; blk < 8; ++blk) {
#pragma unroll
      for (int r = 0; r < 4; ++r) {
        float p = __expf(s[blk][r] - m_new[r]);
        psum[r] += p;
        Pw[wave][(quad * 4 + r) * 136 + blk * 16 + lm] = (bf16_t)p;
      }
    }
#pragma unroll
    for (int d = 1; d < 16; d <<= 1)
#pragma unroll
      for (int r = 0; r < 4; ++r) psum[r] += __shfl_xor(psum[r], d);
#pragma unroll
    for (int r = 0; r < 4; ++r) {
      l_run[r] = l_run[r] * alpha[r] + psum[r];
      m_run[r] = m_new[r];
      o0[r] *= alpha[r];
      o1[r] *= alpha[r];
    }
    // ---- PV ----
    bf16x8 ap[4];
#pragma unroll
    for (int kc = 0; kc < 4; ++kc)
      ap[kc] = *(const bf16x8*)&Pw[wave][lm * 136 + kc * 32 + quad * 8];
#pragma unroll
    for (int kc = 0; kc < 4; ++kc) {
      bf16x8 vb0 = *(const bf16x8*)&VT[lm * 136 + kc * 32 + quad * 8];
      bf16x8 vb1 = *(const bf16x8*)&VT[(16 + lm) * 136 + kc * 32 + quad * 8];
      o0 = __builtin_amdgcn_mfma_f32_16x16x32_bf16(ap[kc], vb0, o0, 0, 0, 0);
      o1 = __builtin_amdgcn_mfma_f32_16x16x32_bf16(ap[kc], vb1, o1, 0, 0, 0);
    }
  }
  // ---- epilogue ----
#pragma unroll
  for (int r = 0; r < 4; ++r) {
    int q = q0 + quad * 4 + r;
    if (q < NQ) {
      float inv = 1.0f / l_run[r];
      size_t base = ((size_t)q * BB + b) * 256 + h * 32;
      sa[base + lm] = (bf16_t)(o0[r] * inv);
      sa[base + 16 + lm] = (bf16_t)(o1[r] * inv);
    }
  }
}

// ---------------------------------------------------------------------------
// deformable sampling: block per row r=q*8+b; out bf16 [7200,256]
// ---------------------------------------------------------------------------
__global__ __launch_bounds__(256) void deform_kernel(
    const bf16_t* __restrict__ value, const float* __restrict__ offs,
    const float* __restrict__ awl, const float* __restrict__ refp,
    bf16_t* __restrict__ out)
{
  __shared__ float logits[160];
  __shared__ float wfin[160][4];
  __shared__ int   tidx[160][4];
  __shared__ float hmax[8], hsum[8];
  const int r = blockIdx.x;
  const int b = r & 7;
  const int t = threadIdx.x;
  if (t < 160) {
    int i20 = t % 20;
    int l = i20 / 5;
    logits[t] = awl[(size_t)r * 160 + t];
    float ox = offs[(size_t)r * 320 + t * 2];
    float oy = offs[(size_t)r * 320 + t * 2 + 1];
    const float* rp = refp + ((size_t)r * LL + l) * 4;
    int Wl = 128 >> l;
    int st = (l == 0) ? 0 : (l == 1) ? 16384 : (l == 2) ? 20480 : 21504;
    float lx = rp[0] + ox * 0.1f * rp[2];
    float ly = rp[1] + oy * 0.1f * rp[3];
    float xx = lx * (float)Wl - 0.5f;
    float yy = ly * (float)Wl - 0.5f;
    float x0f = floorf(xx), y0f = floorf(yy);
    float fx = xx - x0f, fy = yy - y0f;
    int x0 = (int)x0f, y0 = (int)y0f;
#pragma unroll
    for (int tap = 0; tap < 4; ++tap) {
      int dx = tap & 1, dy = tap >> 1;
      int xi = x0 + dx, yi = y0 + dy;
      float w = (dx ? fx : 1.0f - fx) * (dy ? fy : 1.0f - fy);
      bool valid = (xi >= 0) & (xi < Wl) & (yi >= 0) & (yi < Wl);
      int xc = min(max(xi, 0), Wl - 1);
      int yc = min(max(yi, 0), Wl - 1);
      tidx[t][tap] = (st + yc * Wl + xc) * BB + b;
      wfin[t][tap] = valid ? w : 0.0f;
    }
  }
  __syncthreads();
  if (t < 8) {
    float m = -1e30f;
    for (int i = 0; i < 20; ++i) m = fmaxf(m, logits[t * 20 + i]);
    float s = 0.f;
    for (int i = 0; i < 20; ++i) s += __expf(logits[t * 20 + i] - m);
    hmax[t] = m; hsum[t] = s;
  }
  __syncthreads();
  if (t < 160) {
    int h = t / 20;
    float p = __expf(logits[t] - hmax[h]) / hsum[h];
#pragma unroll
    for (int tap = 0; tap < 4; ++tap) wfin[t][tap] *= p;
  }
  __syncthreads();
  const int h = t >> 5, d = t & 31;
  const bf16_t* vbase = value + h * 32 + d;
  float acc = 0.f;
#pragma unroll 4
  for (int i = 0; i < 20; ++i) {
    int e = h * 20 + i;
#pragma unroll
    for (int tap = 0; tap < 4; ++tap) {
      float w = wfin[e][tap];
      float v = (float)vbase[(size_t)tidx[e][tap] * 256];
      acc = fmaf(w, v, acc);
    }
  }
  out[(size_t)r * 256 + t] = (bf16_t)acc;
}

// ---------------------------------------------------------------------------
// launch
// ---------------------------------------------------------------------------
static inline int tiles(int x) { return (x + 127) >> 7; }

extern "C" void kernel_launch(void* const* d_in, const int* in_sizes, int n_in,
                              void* d_out, int out_size, void* d_ws, size_t ws_size,
                              hipStream_t stream) {
  const float* tgt     = (const float*)d_in[0];
  const float* pos     = (const float*)d_in[1];
  const float* refp    = (const float*)d_in[2];
  const float* memory  = (const float*)d_in[3];
  const float* sa_in_w = (const float*)d_in[4];
  const float* sa_in_b = (const float*)d_in[5];
  const float* sa_out_w= (const float*)d_in[6];
  const float* sa_out_b= (const float*)d_in[7];
  const float* off_w   = (const float*)d_in[8];
  const float* off_b   = (const float*)d_in[9];
  const float* aw_w    = (const float*)d_in[10];
  const float* aw_b    = (const float*)d_in[11];
  const float* val_w   = (const float*)d_in[12];
  const float* val_b   = (const float*)d_in[13];
  const float* co_w    = (const float*)d_in[14];
  const float* co_b    = (const float*)d_in[15];
  const float* w1      = (const float*)d_in[16];
  const float* b1      = (const float*)d_in[17];
  const float* w2      = (const float*)d_in[18];
  const float* b2      = (const float*)d_in[19];
  const float* ln1_g   = (const float*)d_in[20];
  const float* ln1_b   = (const float*)d_in[21];
  const float* ln2_g   = (const float*)d_in[22];
  const float* ln2_b   = (const float*)d_in[23];
  const float* ln3_g   = (const float*)d_in[24];
  const float* ln3_b   = (const float*)d_in[25];

  char* ws = (char*)d_ws;
  bf16_t* value_bf = (bf16_t*)ws;                        // 89,128,960
  bf16_t* qk_bf    = (bf16_t*)(ws + 89128960);           // 7,372,800 | h1_bf 14,745,600
  bf16_t* h1_bf    = qk_bf;
  bf16_t* qsum_bf  = (bf16_t*)(ws + 103874560);          // 3,686,400
  bf16_t* vp_bf    = (bf16_t*)(ws + 107560960);          // 3,686,400
  bf16_t* sa_bf    = (bf16_t*)(ws + 111247360);          // 3,686,400
  float*  tgt2     = (float*)(ws + 114933760);           // 7,372,800
  bf16_t* query_bf = (bf16_t*)(ws + 122306560);          // 3,686,400
  float*  offs     = (float*)(ws + 125992960);           // 9,216,000
  float*  awl      = (float*)(ws + 135208960);           // 4,608,000
  bf16_t* ca_bf    = (bf16_t*)(ws + 139816960);          // 3,686,400
  float*  gout     = (float*)(ws + 143503360);           // 7,372,800
  float*  tgt3     = (float*)(ws + 150876160);           // 7,372,800
  bf16_t* tgt3_bf  = (bf16_t*)(ws + 158248960);          // 3,686,400
  bf16_t* wbf      = (bf16_t*)(ws + 161935360);          // 2,080,768
  bf16_t* sa_in_wb = wbf;
  bf16_t* sa_out_wb= wbf + 196608;
  bf16_t* off_wb   = wbf + 262144;
  bf16_t* aw_wb    = wbf + 344064;
  bf16_t* val_wb   = wbf + 385024;
  bf16_t* co_wb    = wbf + 450560;
  bf16_t* w1b      = wbf + 516096;
  bf16_t* w2b      = wbf + 778240;
  float*  outp     = (float*)d_out;

  const int n8q = MQ * DD / 8;

  auto cvt = [&](const float* in, bf16_t* out, int n) {
    int n8 = n / 8;
    cvt_kernel<<<dim3((n8 + 255) / 256), 256, 0, stream>>>(in, out, n8);
  };
  cvt(sa_in_w, sa_in_wb, 196608);
  cvt(sa_out_w, sa_out_wb, 65536);
  cvt(off_w, off_wb, 81920);
  cvt(aw_w, aw_wb, 40960);
  cvt(val_w, val_wb, 65536);
  cvt(co_w, co_wb, 65536);
  cvt(w1, w1b, 262144);
  cvt(w2, w2b, 262144);

  // ---- self-attention ----
  addpos_kernel<<<dim3((n8q + 255) / 256), 256, 0, stream>>>(tgt, pos, qsum_bf, n8q);
  gemm128<bf16_t, 0, bf16_t><<<dim3(tiles(MQ) * 4), 256, 0, stream>>>(
      qsum_bf, sa_in_wb, sa_in_b, qk_bf, MQ, 512, 256, 4);
  gemm128<float, 0, bf16_t><<<dim3(tiles(MQ) * 2), 256, 0, stream>>>(
      tgt, sa_in_wb + 512 * 256, sa_in_b + 512, vp_bf, MQ, 256, 256, 2);
  attn_mfma<<<dim3(64, 15), 256, 0, stream>>>(qk_bf, vp_bf, sa_bf);
  gemm128<bf16_t, 0, float><<<dim3(tiles(MQ) * 2), 256, 0, stream>>>(
      sa_bf, sa_out_wb, sa_out_b, gout, MQ, 256, 256, 2);
  lnres_kernel<0><<<dim3((MQ + 3) / 4), 256, 0, stream>>>(
      gout, tgt, ln2_g, ln2_b, tgt2, (bf16_t*)nullptr, MQ);

  // ---- deformable cross-attention ----
  addpos_kernel<<<dim3((n8q + 255) / 256), 256, 0, stream>>>(tgt2, pos, query_bf, n8q);
  gemm128<float, 0, bf16_t><<<dim3(tiles(MV) * 2), 256, 0, stream>>>(
      memory, val_wb, val_b, value_bf, MV, 256, 256, 2);
  gemm128<bf16_t, 0, float><<<dim3(tiles(MQ) * 3), 256, 0, stream>>>(
      query_bf, off_wb, off_b, offs, MQ, 320, 256, 3);
  gemm128<bf16_t, 0, float><<<dim3(tiles(MQ) * 2), 256, 0, stream>>>(
      query_bf, aw_wb, aw_b, awl, MQ, 160, 256, 2);
  deform_kernel<<<dim3(MQ), 256, 0, stream>>>(value_bf, offs, awl, refp, ca_bf);
  gemm128<bf16_t, 0, float><<<dim3(tiles(MQ) * 2), 256, 0, stream>>>(
      ca_bf, co_wb, co_b, gout, MQ, 256, 256, 2);
  lnres_kernel<1><<<dim3((MQ + 3) / 4), 256, 0, stream>>>(
      gout, tgt2, ln1_g, ln1_b, tgt3, tgt3_bf, MQ);

  // ---- FFN ----
  gemm128<bf16_t, 1, bf16_t><<<dim3(tiles(MQ) * 8), 256, 0, stream>>>(
      tgt3_bf, w1b, b1, h1_bf, MQ, DFF, 256, 8);
  gemm128<bf16_t, 0, float><<<dim3(tiles(MQ) * 2), 256, 0, stream>>>(
      h1_bf, w2b, b2, gout, MQ, 256, DFF, 2);
  lnres_kernel<0><<<dim3((MQ + 3) / 4), 256, 0, stream>>>(
      gout, tgt3, ln3_g, ln3_b, outp, (bf16_t*)nullptr, MQ);

  (void)in_sizes; (void)n_in; (void)out_size; (void)ws_size;
}

// Round 4
// 608.728 us; speedup vs baseline: 3.1673x; 1.0339x over previous
//
#include <hip/hip_runtime.h>
#include <hip/hip_bf16.h>

#define NQ   900
#define BB   8
#define DD   256
#define HH   8
#define DH   32
#define LL   4
#define PP   5
#define SS   21760
#define DFF  1024
#define MQ   (NQ*BB)      // 7200
#define MV   (SS*BB)      // 174080

typedef __bf16 bf16_t;
typedef __bf16 bf16x8 __attribute__((ext_vector_type(8)));
typedef __bf16 bf16x4 __attribute__((ext_vector_type(4)));
typedef float  f32x4  __attribute__((ext_vector_type(4)));

// async global->LDS 16B copy
__device__ __forceinline__ void async16(const void* g, void* l) {
  __builtin_amdgcn_global_load_lds(
      (const __attribute__((address_space(1))) unsigned int*)g,
      (__attribute__((address_space(3))) unsigned int*)l, 16, 0, 0);
}

// ---------------------------------------------------------------------------
// vgemm: C[M,N] = A[M,256] @ W[N,256]^T + bias.  K=256 fixed.
// Block = 256 rows x 64 cols, 4 waves (wave w owns rows w*64..+63).
// W 64-col whole-K tile (32 KB) staged in LDS ONCE (single barrier), then the
// K-loop is barrier-free: A streams global->VGPR (compiler pipelines with
// fine-grained vmcnt), B frags ds_read_b128 <=2-way via XOR chunk swizzle.
// ---------------------------------------------------------------------------
template<typename AT, typename OT, int RELU>
__global__ __launch_bounds__(256) void vgemm(
    const AT* __restrict__ A, const bf16_t* __restrict__ W,
    const float* __restrict__ bias, OT* __restrict__ C,
    int M, int N, int nt)
{
  constexpr bool AF = (sizeof(AT) == 4);
  __shared__ __align__(16) bf16_t Ws[64 * 256];   // 32 KB, [col][chunk^swz]
  const int blk = blockIdx.x;
  const int tn = blk % nt, tm = blk / nt;
  const int n0 = tn << 6, m0 = tm << 8;
  const int t = threadIdx.x, wave = t >> 6, lane = t & 63;
  const int lm = lane & 15, quad = lane >> 4;

  // ---- stage W whole-K, chunk-swizzled: stored chunk p holds k-chunk p^(col&31)
#pragma unroll
  for (int j = 0; j < 8; ++j) {
    int flat = j * 4096 + t * 16;                 // byte offset in Ws
    int col = flat >> 9;                          // 512 B per col
    int kc = ((flat >> 4) & 31) ^ (col & 31);
    int colg = n0 + col; if (colg >= N) colg = N - 1;
    async16(&W[(size_t)colg * 256 + kc * 8], (char*)Ws + flat);
  }
  __syncthreads();   // ONLY barrier before the K-loop

  f32x4 acc[4][4];
#pragma unroll
  for (int i = 0; i < 4; ++i)
#pragma unroll
    for (int j = 0; j < 4; ++j) acc[i][j] = (f32x4){0.f, 0.f, 0.f, 0.f};

#pragma unroll 2
  for (int k0 = 0; k0 < 256; k0 += 32) {
    const int ki = k0 >> 3;
    bf16x8 bfr[4];
#pragma unroll
    for (int ni = 0; ni < 4; ++ni) {
      int col = ni * 16 + lm;
      int ch = (ki + quad) ^ (col & 31);
      bfr[ni] = *(const bf16x8*)&Ws[col * 256 + ch * 8];
    }
    bf16x8 af[4];
#pragma unroll
    for (int mi = 0; mi < 4; ++mi) {
      int row = m0 + wave * 64 + mi * 16 + lm; if (row >= M) row = M - 1;
      if constexpr (AF) {
        const float* ap = A + (size_t)row * 256 + k0 + quad * 8;
        f32x4 lo = *(const f32x4*)ap;
        f32x4 hi = *(const f32x4*)(ap + 4);
        bf16x8 f;
#pragma unroll
        for (int j = 0; j < 4; ++j) { f[j] = (bf16_t)lo[j]; f[4 + j] = (bf16_t)hi[j]; }
        af[mi] = f;
      } else {
        af[mi] = *(const bf16x8*)&A[(size_t)row * 256 + k0 + quad * 8];
      }
    }
#pragma unroll
    for (int mi = 0; mi < 4; ++mi)
#pragma unroll
      for (int ni = 0; ni < 4; ++ni)
        acc[mi][ni] = __builtin_amdgcn_mfma_f32_16x16x32_bf16(af[mi], bfr[ni], acc[mi][ni], 0, 0, 0);
  }

  // bias (C/D layout: col = lane&15, row = quad*4+reg  [m89-verified])
  float bv[4];
#pragma unroll
  for (int ni = 0; ni < 4; ++ni) {
    int c = n0 + ni * 16 + lm;
    bv[ni] = (c < N) ? bias[c] : 0.f;
  }

  if constexpr (sizeof(OT) == 4) {
    // direct f32 stores
#pragma unroll
    for (int mi = 0; mi < 4; ++mi) {
#pragma unroll
      for (int r = 0; r < 4; ++r) {
        int row = m0 + wave * 64 + mi * 16 + quad * 4 + r;
        if (row < M) {
#pragma unroll
          for (int ni = 0; ni < 4; ++ni) {
            int col = n0 + ni * 16 + lm;
            if (col < N) {
              float v = acc[mi][ni][r] + bv[ni];
              if (RELU) v = fmaxf(v, 0.f);
              C[(size_t)row * N + col] = (OT)v;
            }
          }
        }
      }
    }
  } else {
    // bf16 out: LDS transpose (reuse Ws) for coalesced 16B stores
    __syncthreads();
    bf16_t* Os = Ws;   // 256 rows x 64 cols = 32 KB
#pragma unroll
    for (int mi = 0; mi < 4; ++mi)
#pragma unroll
      for (int r = 0; r < 4; ++r) {
        int rl = wave * 64 + mi * 16 + quad * 4 + r;
#pragma unroll
        for (int ni = 0; ni < 4; ++ni) {
          float v = acc[mi][ni][r] + bv[ni];
          if (RELU) v = fmaxf(v, 0.f);
          Os[rl * 64 + ni * 16 + lm] = (bf16_t)v;
        }
      }
    __syncthreads();
#pragma unroll
    for (int i = 0; i < 8; ++i) {
      int fe = i * 2048 + t * 8;       // element in Os
      int rl = fe >> 6, cl = fe & 63;
      int row = m0 + rl, colg = n0 + cl;
      if (row < M && colg < N)
        *(bf16x8*)&C[(size_t)row * N + colg] = *(const bf16x8*)&Os[fe];
    }
  }
}

// ---------------------------------------------------------------------------
// m97-style GEMM kept for FFN2 (K=1024): C[M,N] = A@W^T + bias
// ---------------------------------------------------------------------------
template<typename AT, int EPI, typename OT>
__global__ __launch_bounds__(256) void gemm128(
    const AT* __restrict__ A, const bf16_t* __restrict__ W,
    const float* __restrict__ bias, OT* __restrict__ C,
    int M, int N, int K, int tiles_n)
{
  __shared__ __align__(16) bf16_t As[128 * 32];
  __shared__ __align__(16) bf16_t Bs[128 * 32];
  const int tm = blockIdx.x / tiles_n;
  const int tn = blockIdx.x - tm * tiles_n;
  const int m0 = tm << 7, n0 = tn << 7;
  const int t = threadIdx.x;
  const int wave = t >> 6, lane = t & 63;
  const int wr = wave >> 1, wc = wave & 1;
  const int lm = lane & 15, kq = lane >> 4;

  f32x4 acc[4][4];
#pragma unroll
  for (int i = 0; i < 4; ++i)
#pragma unroll
    for (int j = 0; j < 4; ++j) acc[i][j] = (f32x4){0.f, 0.f, 0.f, 0.f};

  for (int k0 = 0; k0 < K; k0 += 32) {
    __syncthreads();
#pragma unroll
    for (int i = 0; i < 2; ++i) {
      int flat = i * 4096 + t * 16;
      int row = flat >> 6;
      int cl = (flat >> 4) & 3;
      int cg = cl ^ ((row >> 1) & 3);
      int grow = m0 + row; if (grow >= M) grow = M - 1;
      async16(&A[(size_t)grow * K + k0 + cg * 8], (char*)As + flat);
    }
#pragma unroll
    for (int i = 0; i < 2; ++i) {
      int flat = i * 4096 + t * 16;
      int row = flat >> 6;
      int cl = (flat >> 4) & 3;
      int cg = cl ^ ((row >> 1) & 3);
      int grow = n0 + row; if (grow >= N) grow = N - 1;
      async16(&W[(size_t)grow * K + k0 + cg * 8], (char*)Bs + flat);
    }
    __syncthreads();

    bf16x8 af[4], bfr[4];
#pragma unroll
    for (int mi = 0; mi < 4; ++mi) {
      int row = wr * 64 + mi * 16 + lm;
      int s = (row >> 1) & 3;
      af[mi] = *(const bf16x8*)((const bf16_t*)As + row * 32 + ((kq ^ s) << 3));
    }
#pragma unroll
    for (int ni = 0; ni < 4; ++ni) {
      int row = wc * 64 + ni * 16 + lm;
      int s = (row >> 1) & 3;
      bfr[ni] = *(const bf16x8*)(Bs + row * 32 + ((kq ^ s) << 3));
    }
#pragma unroll
    for (int mi = 0; mi < 4; ++mi)
#pragma unroll
      for (int ni = 0; ni < 4; ++ni)
        acc[mi][ni] = __builtin_amdgcn_mfma_f32_16x16x32_bf16(af[mi], bfr[ni], acc[mi][ni], 0, 0, 0);
  }

  const int colb = n0 + wc * 64 + lm;
  float bv[4]; bool cok[4];
#pragma unroll
  for (int ni = 0; ni < 4; ++ni) {
    int c = colb + ni * 16;
    cok[ni] = (c < N);
    bv[ni] = cok[ni] ? bias[c] : 0.f;
  }
#pragma unroll
  for (int mi = 0; mi < 4; ++mi) {
    int rbase = m0 + wr * 64 + mi * 16 + kq * 4;
#pragma unroll
    for (int reg = 0; reg < 4; ++reg) {
      int r = rbase + reg;
      if (r < M) {
#pragma unroll
        for (int ni = 0; ni < 4; ++ni) if (cok[ni]) {
          float v = acc[mi][ni][reg] + bv[ni];
          if (EPI == 1) v = fmaxf(v, 0.f);
          C[(size_t)r * N + colb + ni * 16] = (OT)v;
        }
      }
    }
  }
}

// ---------------------------------------------------------------------------
// fused weight convert: all 8 f32 weight matrices -> contiguous bf16 region
// ---------------------------------------------------------------------------
__global__ __launch_bounds__(256) void cvt_all(
    const float* __restrict__ s0, const float* __restrict__ s1,
    const float* __restrict__ s2, const float* __restrict__ s3,
    const float* __restrict__ s4, const float* __restrict__ s5,
    const float* __restrict__ s6, const float* __restrict__ s7,
    bf16_t* __restrict__ dst)
{
  int i = blockIdx.x * 256 + threadIdx.x;
  if (i >= 130048) return;
  const float* s; int base;
  if (i < 24576)      { s = s0; base = 0; }
  else if (i < 32768) { s = s1; base = 24576; }
  else if (i < 43008) { s = s2; base = 32768; }
  else if (i < 48128) { s = s3; base = 43008; }
  else if (i < 56320) { s = s4; base = 48128; }
  else if (i < 64512) { s = s5; base = 56320; }
  else if (i < 97280) { s = s6; base = 64512; }
  else                { s = s7; base = 97280; }
  int li = i - base;
  f32x4 x0 = ((const f32x4*)s)[2 * li], x1 = ((const f32x4*)s)[2 * li + 1];
  bf16x8 r;
#pragma unroll
  for (int j = 0; j < 4; ++j) { r[j] = (bf16_t)x0[j]; r[4 + j] = (bf16_t)x1[j]; }
  ((bf16x8*)dst)[i] = r;
}

__global__ __launch_bounds__(256) void addpos_kernel(
    const float* __restrict__ a, const float* __restrict__ b,
    bf16_t* __restrict__ o, int n8)
{
  int i = blockIdx.x * 256 + threadIdx.x;
  if (i < n8) {
    f32x4 x0 = ((const f32x4*)a)[2 * i], x1 = ((const f32x4*)a)[2 * i + 1];
    f32x4 y0 = ((const f32x4*)b)[2 * i], y1 = ((const f32x4*)b)[2 * i + 1];
    bf16x8 r;
#pragma unroll
    for (int j = 0; j < 4; ++j) { r[j] = (bf16_t)(x0[j] + y0[j]); r[4 + j] = (bf16_t)(x1[j] + y1[j]); }
    ((bf16x8*)o)[i] = r;
  }
}

// ---------------------------------------------------------------------------
// residual + layernorm (f32 out, optional bf16 second output), D=256
// ---------------------------------------------------------------------------
template<int WBF>
__global__ __launch_bounds__(256) void lnres_kernel(
    const float* __restrict__ x, const float* __restrict__ res,
    const float* __restrict__ g, const float* __restrict__ bta,
    float* __restrict__ out, bf16_t* __restrict__ outb, int rows)
{
  int wave = threadIdx.x >> 6, lane = threadIdx.x & 63;
  int row = blockIdx.x * 4 + wave;
  if (row >= rows) return;
  const float4* xp = (const float4*)(x + (size_t)row * DD);
  const float4* rp = (const float4*)(res + (size_t)row * DD);
  float4 v = xp[lane], rr = rp[lane];
  float a0 = v.x + rr.x, a1 = v.y + rr.y, a2 = v.z + rr.z, a3 = v.w + rr.w;
  float s = a0 + a1 + a2 + a3;
#pragma unroll
  for (int off = 32; off; off >>= 1) s += __shfl_xor(s, off);
  float mean = s * (1.0f / DD);
  float d0 = a0 - mean, d1 = a1 - mean, d2 = a2 - mean, d3 = a3 - mean;
  float vs = d0 * d0 + d1 * d1 + d2 * d2 + d3 * d3;
#pragma unroll
  for (int off = 32; off; off >>= 1) vs += __shfl_xor(vs, off);
  float inv = rsqrtf(vs * (1.0f / DD) + 1e-5f);
  float4 gg = ((const float4*)g)[lane];
  float4 bb = ((const float4*)bta)[lane];
  float o0 = d0 * inv * gg.x + bb.x, o1 = d1 * inv * gg.y + bb.y;
  float o2 = d2 * inv * gg.z + bb.z, o3 = d3 * inv * gg.w + bb.w;
  float4 o; o.x = o0; o.y = o1; o.z = o2; o.w = o3;
  ((float4*)(out + (size_t)row * DD))[lane] = o;
  if (WBF) {
    bf16x4 ob; ob[0] = (bf16_t)o0; ob[1] = (bf16_t)o1; ob[2] = (bf16_t)o2; ob[3] = (bf16_t)o3;
    ((bf16x4*)(outb + (size_t)row * DD))[lane] = ob;
  }
}

// ---------------------------------------------------------------------------
// MFMA flash self-attention (as R3). Block = (b,h) x 64-q tile.
// ---------------------------------------------------------------------------
__global__ __launch_bounds__(256) void attn_mfma(
    const bf16_t* __restrict__ qk, const bf16_t* __restrict__ vp,
    bf16_t* __restrict__ sa)
{
  __shared__ __align__(16) bf16_t Ks[128 * 32];
  __shared__ __align__(16) bf16_t VT[32 * 136];
  __shared__ __align__(16) bf16_t Pw[4][16 * 136];
  const int bh = blockIdx.x;
  const int b = bh & 7, h = bh >> 3;
  const int qt = blockIdx.y;
  const int t = threadIdx.x, wave = t >> 6, lane = t & 63;
  const int lm = lane & 15, quad = lane >> 4;
  const int q0 = qt * 64 + wave * 16;

  int qrow = q0 + lm; if (qrow > NQ - 1) qrow = NQ - 1;
  bf16x8 aqr = *(const bf16x8*)&qk[((size_t)qrow * BB + b) * 512 + h * 32 + quad * 8];
  bf16x8 aq;
#pragma unroll
  for (int j = 0; j < 8; ++j) aq[j] = (bf16_t)((float)aqr[j] * 0.17677669529663687f);

  f32x4 m_run = {-1e30f, -1e30f, -1e30f, -1e30f};
  f32x4 l_run = {0.f, 0.f, 0.f, 0.f};
  f32x4 o0 = {0.f, 0.f, 0.f, 0.f}, o1 = {0.f, 0.f, 0.f, 0.f};
  const f32x4 zero = {0.f, 0.f, 0.f, 0.f};

  for (int c = 0; c < 8; ++c) {
    const int k0 = c * 128;
    __syncthreads();
#pragma unroll
    for (int i = 0; i < 2; ++i) {
      int flat = i * 4096 + t * 16;
      int row = flat >> 6;
      int cl = (flat >> 4) & 3;
      int cg = cl ^ ((row >> 1) & 3);
      int key = k0 + row; if (key > NQ - 1) key = NQ - 1;
      async16(&qk[((size_t)key * BB + b) * 512 + 256 + h * 32 + cg * 8], (char*)Ks + flat);
    }
#pragma unroll
    for (int i = 0; i < 2; ++i) {
      int idx = t * 2 + i;
      int key = idx >> 2, dc = idx & 3;
      int gk = k0 + key;
      if (gk < NQ) {
        bf16x8 vv = *(const bf16x8*)&vp[((size_t)gk * BB + b) * 256 + h * 32 + dc * 8];
#pragma unroll
        for (int u = 0; u < 8; ++u) VT[(dc * 8 + u) * 136 + key] = vv[u];
      } else {
#pragma unroll
        for (int u = 0; u < 8; ++u) VT[(dc * 8 + u) * 136 + key] = (bf16_t)0.f;
      }
    }
    __syncthreads();

    f32x4 s[8];
#pragma unroll
    for (int blk = 0; blk < 8; ++blk) {
      int row = blk * 16 + lm;
      int sw = (row >> 1) & 3;
      bf16x8 kb = *(const bf16x8*)&Ks[row * 32 + ((quad ^ sw) << 3)];
      s[blk] = __builtin_amdgcn_mfma_f32_16x16x32_bf16(aq, kb, zero, 0, 0, 0);
    }
    if (c == 7) {
#pragma unroll
      for (int blk = 0; blk < 8; ++blk) {
        if (k0 + blk * 16 + lm >= NQ) {
#pragma unroll
          for (int r = 0; r < 4; ++r) s[blk][r] = -1e30f;
        }
      }
    }
    f32x4 mx = s[0];
#pragma unroll
    for (int blk = 1; blk < 8; ++blk)
#pragma unroll
      for (int r = 0; r < 4; ++r) mx[r] = fmaxf(mx[r], s[blk][r]);
#pragma unroll
    for (int d = 1; d < 16; d <<= 1)
#pragma unroll
      for (int r = 0; r < 4; ++r) mx[r] = fmaxf(mx[r], __shfl_xor(mx[r], d));
    f32x4 m_new, alpha;
#pragma unroll
    for (int r = 0; r < 4; ++r) {
      m_new[r] = fmaxf(m_run[r], mx[r]);
      alpha[r] = __expf(m_run[r] - m_new[r]);
    }
    f32x4 psum = {0.f, 0.f, 0.f, 0.f};
#pragma unroll
    for (int blk = 0; blk < 8; ++blk) {
#pragma unroll
      for (int r = 0; r < 4; ++r) {
        float p = __expf(s[blk][r] - m_new[r]);
        psum[r] += p;
        Pw[wave][(quad * 4 + r) * 136 + blk * 16 + lm] = (bf16_t)p;
      }
    }
#pragma unroll
    for (int d = 1; d < 16; d <<= 1)
#pragma unroll
      for (int r = 0; r < 4; ++r) psum[r] += __shfl_xor(psum[r], d);
#pragma unroll
    for (int r = 0; r < 4; ++r) {
      l_run[r] = l_run[r] * alpha[r] + psum[r];
      m_run[r] = m_new[r];
      o0[r] *= alpha[r];
      o1[r] *= alpha[r];
    }
    bf16x8 ap[4];
#pragma unroll
    for (int kc = 0; kc < 4; ++kc)
      ap[kc] = *(const bf16x8*)&Pw[wave][lm * 136 + kc * 32 + quad * 8];
#pragma unroll
    for (int kc = 0; kc < 4; ++kc) {
      bf16x8 vb0 = *(const bf16x8*)&VT[lm * 136 + kc * 32 + quad * 8];
      bf16x8 vb1 = *(const bf16x8*)&VT[(16 + lm) * 136 + kc * 32 + quad * 8];
      o0 = __builtin_amdgcn_mfma_f32_16x16x32_bf16(ap[kc], vb0, o0, 0, 0, 0);
      o1 = __builtin_amdgcn_mfma_f32_16x16x32_bf16(ap[kc], vb1, o1, 0, 0, 0);
    }
  }
#pragma unroll
  for (int r = 0; r < 4; ++r) {
    int q = q0 + quad * 4 + r;
    if (q < NQ) {
      float inv = 1.0f / l_run[r];
      size_t base = ((size_t)q * BB + b) * 256 + h * 32;
      sa[base + lm] = (bf16_t)(o0[r] * inv);
      sa[base + 16 + lm] = (bf16_t)(o1[r] * inv);
    }
  }
}

// ---------------------------------------------------------------------------
// deformable sampling (as R3)
// ---------------------------------------------------------------------------
__global__ __launch_bounds__(256) void deform_kernel(
    const bf16_t* __restrict__ value, const float* __restrict__ offs,
    const float* __restrict__ awl, const float* __restrict__ refp,
    bf16_t* __restrict__ out)
{
  __shared__ float logits[160];
  __shared__ float wfin[160][4];
  __shared__ int   tidx[160][4];
  __shared__ float hmax[8], hsum[8];
  const int r = blockIdx.x;
  const int b = r & 7;
  const int t = threadIdx.x;
  if (t < 160) {
    int i20 = t % 20;
    int l = i20 / 5;
    logits[t] = awl[(size_t)r * 160 + t];
    float ox = offs[(size_t)r * 320 + t * 2];
    float oy = offs[(size_t)r * 320 + t * 2 + 1];
    const float* rp = refp + ((size_t)r * LL + l) * 4;
    int Wl = 128 >> l;
    int st = (l == 0) ? 0 : (l == 1) ? 16384 : (l == 2) ? 20480 : 21504;
    float lx = rp[0] + ox * 0.1f * rp[2];
    float ly = rp[1] + oy * 0.1f * rp[3];
    float xx = lx * (float)Wl - 0.5f;
    float yy = ly * (float)Wl - 0.5f;
    float x0f = floorf(xx), y0f = floorf(yy);
    float fx = xx - x0f, fy = yy - y0f;
    int x0 = (int)x0f, y0 = (int)y0f;
#pragma unroll
    for (int tap = 0; tap < 4; ++tap) {
      int dx = tap & 1, dy = tap >> 1;
      int xi = x0 + dx, yi = y0 + dy;
      float w = (dx ? fx : 1.0f - fx) * (dy ? fy : 1.0f - fy);
      bool valid = (xi >= 0) & (xi < Wl) & (yi >= 0) & (yi < Wl);
      int xc = min(max(xi, 0), Wl - 1);
      int yc = min(max(yi, 0), Wl - 1);
      tidx[t][tap] = (st + yc * Wl + xc) * BB + b;
      wfin[t][tap] = valid ? w : 0.0f;
    }
  }
  __syncthreads();
  if (t < 8) {
    float m = -1e30f;
    for (int i = 0; i < 20; ++i) m = fmaxf(m, logits[t * 20 + i]);
    float s = 0.f;
    for (int i = 0; i < 20; ++i) s += __expf(logits[t * 20 + i] - m);
    hmax[t] = m; hsum[t] = s;
  }
  __syncthreads();
  if (t < 160) {
    int h = t / 20;
    float p = __expf(logits[t] - hmax[h]) / hsum[h];
#pragma unroll
    for (int tap = 0; tap < 4; ++tap) wfin[t][tap] *= p;
  }
  __syncthreads();
  const int h = t >> 5, d = t & 31;
  const bf16_t* vbase = value + h * 32 + d;
  float acc = 0.f;
#pragma unroll 4
  for (int i = 0; i < 20; ++i) {
    int e = h * 20 + i;
#pragma unroll
    for (int tap = 0; tap < 4; ++tap) {
      float w = wfin[e][tap];
      float v = (float)vbase[(size_t)tidx[e][tap] * 256];
      acc = fmaf(w, v, acc);
    }
  }
  out[(size_t)r * 256 + t] = (bf16_t)acc;
}

// ---------------------------------------------------------------------------
// launch
// ---------------------------------------------------------------------------
static inline int tiles(int x) { return (x + 127) >> 7; }

extern "C" void kernel_launch(void* const* d_in, const int* in_sizes, int n_in,
                              void* d_out, int out_size, void* d_ws, size_t ws_size,
                              hipStream_t stream) {
  const float* tgt     = (const float*)d_in[0];
  const float* pos     = (const float*)d_in[1];
  const float* refp    = (const float*)d_in[2];
  const float* memory  = (const float*)d_in[3];
  const float* sa_in_w = (const float*)d_in[4];
  const float* sa_in_b = (const float*)d_in[5];
  const float* sa_out_w= (const float*)d_in[6];
  const float* sa_out_b= (const float*)d_in[7];
  const float* off_w   = (const float*)d_in[8];
  const float* off_b   = (const float*)d_in[9];
  const float* aw_w    = (const float*)d_in[10];
  const float* aw_b    = (const float*)d_in[11];
  const float* val_w   = (const float*)d_in[12];
  const float* val_b   = (const float*)d_in[13];
  const float* co_w    = (const float*)d_in[14];
  const float* co_b    = (const float*)d_in[15];
  const float* w1      = (const float*)d_in[16];
  const float* b1      = (const float*)d_in[17];
  const float* w2      = (const float*)d_in[18];
  const float* b2      = (const float*)d_in[19];
  const float* ln1_g   = (const float*)d_in[20];
  const float* ln1_b   = (const float*)d_in[21];
  const float* ln2_g   = (const float*)d_in[22];
  const float* ln2_b   = (const float*)d_in[23];
  const float* ln3_g   = (const float*)d_in[24];
  const float* ln3_b   = (const float*)d_in[25];

  char* ws = (char*)d_ws;
  bf16_t* value_bf = (bf16_t*)ws;                        // 89,128,960
  bf16_t* qk_bf    = (bf16_t*)(ws + 89128960);           // 7,372,800 | h1_bf 14,745,600
  bf16_t* h1_bf    = qk_bf;
  bf16_t* qsum_bf  = (bf16_t*)(ws + 103874560);          // 3,686,400
  bf16_t* vp_bf    = (bf16_t*)(ws + 107560960);          // 3,686,400
  bf16_t* sa_bf    = (bf16_t*)(ws + 111247360);          // 3,686,400
  float*  tgt2     = (float*)(ws + 114933760);           // 7,372,800
  bf16_t* query_bf = (bf16_t*)(ws + 122306560);          // 3,686,400
  float*  offs     = (float*)(ws + 125992960);           // 9,216,000
  float*  awl      = (float*)(ws + 135208960);           // 4,608,000
  bf16_t* ca_bf    = (bf16_t*)(ws + 139816960);          // 3,686,400
  float*  gout     = (float*)(ws + 143503360);           // 7,372,800
  float*  tgt3     = (float*)(ws + 150876160);           // 7,372,800
  bf16_t* tgt3_bf  = (bf16_t*)(ws + 158248960);          // 3,686,400
  bf16_t* wbf      = (bf16_t*)(ws + 161935360);          // 2,080,768
  bf16_t* sa_in_wb = wbf;
  bf16_t* sa_out_wb= wbf + 196608;
  bf16_t* off_wb   = wbf + 262144;
  bf16_t* aw_wb    = wbf + 344064;
  bf16_t* val_wb   = wbf + 385024;
  bf16_t* co_wb    = wbf + 450560;
  bf16_t* w1b      = wbf + 516096;
  bf16_t* w2b      = wbf + 778240;
  float*  outp     = (float*)d_out;

  const int n8q = MQ * DD / 8;
  const int mtq = (MQ + 255) >> 8;   // 29

  // ---- all weight converts in one launch ----
  cvt_all<<<dim3(508), 256, 0, stream>>>(
      sa_in_w, sa_out_w, off_w, aw_w, val_w, co_w, w1, w2, wbf);

  // ---- self-attention ----
  addpos_kernel<<<dim3((n8q + 255) / 256), 256, 0, stream>>>(tgt, pos, qsum_bf, n8q);
  vgemm<bf16_t, bf16_t, 0><<<dim3(mtq * 8), 256, 0, stream>>>(
      qsum_bf, sa_in_wb, sa_in_b, qk_bf, MQ, 512, 8);
  vgemm<float, bf16_t, 0><<<dim3(mtq * 4), 256, 0, stream>>>(
      tgt, sa_in_wb + 512 * 256, sa_in_b + 512, vp_bf, MQ, 256, 4);
  attn_mfma<<<dim3(64, 15), 256, 0, stream>>>(qk_bf, vp_bf, sa_bf);
  vgemm<bf16_t, float, 0><<<dim3(mtq * 4), 256, 0, stream>>>(
      sa_bf, sa_out_wb, sa_out_b, gout, MQ, 256, 4);
  lnres_kernel<0><<<dim3((MQ + 3) / 4), 256, 0, stream>>>(
      gout, tgt, ln2_g, ln2_b, tgt2, (bf16_t*)nullptr, MQ);

  // ---- deformable cross-attention ----
  addpos_kernel<<<dim3((n8q + 255) / 256), 256, 0, stream>>>(tgt2, pos, query_bf, n8q);
  vgemm<float, bf16_t, 0><<<dim3(680 * 4), 256, 0, stream>>>(
      memory, val_wb, val_b, value_bf, MV, 256, 4);
  vgemm<bf16_t, float, 0><<<dim3(mtq * 5), 256, 0, stream>>>(
      query_bf, off_wb, off_b, offs, MQ, 320, 5);
  vgemm<bf16_t, float, 0><<<dim3(mtq * 3), 256, 0, stream>>>(
      query_bf, aw_wb, aw_b, awl, MQ, 160, 3);
  deform_kernel<<<dim3(MQ), 256, 0, stream>>>(value_bf, offs, awl, refp, ca_bf);
  vgemm<bf16_t, float, 0><<<dim3(mtq * 4), 256, 0, stream>>>(
      ca_bf, co_wb, co_b, gout, MQ, 256, 4);
  lnres_kernel<1><<<dim3((MQ + 3) / 4), 256, 0, stream>>>(
      gout, tgt2, ln1_g, ln1_b, tgt3, tgt3_bf, MQ);

  // ---- FFN ----
  vgemm<bf16_t, bf16_t, 1><<<dim3(mtq * 16), 256, 0, stream>>>(
      tgt3_bf, w1b, b1, h1_bf, MQ, 1024, 16);
  gemm128<bf16_t, 0, float><<<dim3(tiles(MQ) * 2), 256, 0, stream>>>(
      h1_bf, w2b, b2, gout, MQ, 256, DFF, 2);
  lnres_kernel<0><<<dim3((MQ + 3) / 4), 256, 0, stream>>>(
      gout, tgt3, ln3_g, ln3_b, outp, (bf16_t*)nullptr, MQ);

  (void)in_sizes; (void)n_in; (void)out_size; (void)ws_size;
}

// Round 5
// 584.718 us; speedup vs baseline: 3.2974x; 1.0411x over previous
//
#include <hip/hip_runtime.h>
#include <hip/hip_bf16.h>

#define NQ   900
#define BB   8
#define DD   256
#define HH   8
#define DH   32
#define LL   4
#define PP   5
#define SS   21760
#define DFF  1024
#define MQ   (NQ*BB)      // 7200
#define MV   (SS*BB)      // 174080

typedef __bf16 bf16_t;
typedef __bf16 bf16x8 __attribute__((ext_vector_type(8)));
typedef __bf16 bf16x4 __attribute__((ext_vector_type(4)));
typedef float  f32x4  __attribute__((ext_vector_type(4)));

// async global->LDS 16B copy
__device__ __forceinline__ void async16(const void* g, void* l) {
  __builtin_amdgcn_global_load_lds(
      (const __attribute__((address_space(1))) unsigned int*)g,
      (__attribute__((address_space(3))) unsigned int*)l, 16, 0, 0);
}

// ---------------------------------------------------------------------------
// vgemm: C[M,N] = A[M,256] @ W[N,256]^T + bias.  K=256 fixed.
// Block = 256 rows x 64 cols, 4 waves. W whole-K tile (32 KB) staged once;
// K-loop barrier-free. SWZ=1: sibling n-tiles of a row-block share an XCD
// (blk%8 equal) so A is HBM-fetched once per XCD, L2-hit for the rest.
// NT=1: nontemporal C stores (don't evict A from L2).
// ---------------------------------------------------------------------------
template<typename AT, typename OT, int RELU, int SWZ, int NT>
__global__ __launch_bounds__(256) void vgemm(
    const AT* __restrict__ A, const bf16_t* __restrict__ W,
    const float* __restrict__ bias, OT* __restrict__ C,
    int M, int N, int nt)
{
  constexpr bool AF = (sizeof(AT) == 4);
  __shared__ __align__(16) bf16_t Ws[64 * 256];   // 32 KB
  int tn, tm;
  if (SWZ) {
    int u = blockIdx.x >> 3;
    tn = u % nt;
    tm = (u / nt) * 8 + (blockIdx.x & 7);   // all siblings: same blk%8 -> same XCD
  } else {
    tn = blockIdx.x % nt;
    tm = blockIdx.x / nt;
  }
  const int n0 = tn << 6, m0 = tm << 8;
  const int t = threadIdx.x, wave = t >> 6, lane = t & 63;
  const int lm = lane & 15, quad = lane >> 4;

  // stage W whole-K, chunk-swizzled: slot p of col holds k-chunk p^(col&31)
#pragma unroll
  for (int j = 0; j < 8; ++j) {
    int flat = j * 4096 + t * 16;
    int col = flat >> 9;
    int kc = ((flat >> 4) & 31) ^ (col & 31);
    int colg = n0 + col; if (colg >= N) colg = N - 1;
    async16(&W[(size_t)colg * 256 + kc * 8], (char*)Ws + flat);
  }
  __syncthreads();   // only barrier before K-loop

  f32x4 acc[4][4];
#pragma unroll
  for (int i = 0; i < 4; ++i)
#pragma unroll
    for (int j = 0; j < 4; ++j) acc[i][j] = (f32x4){0.f, 0.f, 0.f, 0.f};

#pragma unroll 2
  for (int k0 = 0; k0 < 256; k0 += 32) {
    const int ki = k0 >> 3;
    bf16x8 bfr[4];
#pragma unroll
    for (int ni = 0; ni < 4; ++ni) {
      int col = ni * 16 + lm;
      int ch = (ki + quad) ^ (col & 31);
      bfr[ni] = *(const bf16x8*)&Ws[col * 256 + ch * 8];
    }
    bf16x8 af[4];
#pragma unroll
    for (int mi = 0; mi < 4; ++mi) {
      int row = m0 + wave * 64 + mi * 16 + lm; if (row >= M) row = M - 1;
      if constexpr (AF) {
        const float* ap = A + (size_t)row * 256 + k0 + quad * 8;
        f32x4 lo = *(const f32x4*)ap;
        f32x4 hi = *(const f32x4*)(ap + 4);
        bf16x8 f;
#pragma unroll
        for (int j = 0; j < 4; ++j) { f[j] = (bf16_t)lo[j]; f[4 + j] = (bf16_t)hi[j]; }
        af[mi] = f;
      } else {
        af[mi] = *(const bf16x8*)&A[(size_t)row * 256 + k0 + quad * 8];
      }
    }
#pragma unroll
    for (int mi = 0; mi < 4; ++mi)
#pragma unroll
      for (int ni = 0; ni < 4; ++ni)
        acc[mi][ni] = __builtin_amdgcn_mfma_f32_16x16x32_bf16(af[mi], bfr[ni], acc[mi][ni], 0, 0, 0);
  }

  float bv[4];
#pragma unroll
  for (int ni = 0; ni < 4; ++ni) {
    int c = n0 + ni * 16 + lm;
    bv[ni] = (c < N) ? bias[c] : 0.f;
  }

  if constexpr (sizeof(OT) == 4) {
#pragma unroll
    for (int mi = 0; mi < 4; ++mi) {
#pragma unroll
      for (int r = 0; r < 4; ++r) {
        int row = m0 + wave * 64 + mi * 16 + quad * 4 + r;
        if (row < M) {
#pragma unroll
          for (int ni = 0; ni < 4; ++ni) {
            int col = n0 + ni * 16 + lm;
            if (col < N) {
              float v = acc[mi][ni][r] + bv[ni];
              if (RELU) v = fmaxf(v, 0.f);
              C[(size_t)row * N + col] = (OT)v;
            }
          }
        }
      }
    }
  } else {
    // bf16 out: LDS transpose (reuse Ws) for coalesced 16B stores
    __syncthreads();
    bf16_t* Os = Ws;   // 256 x 64 = 32 KB
#pragma unroll
    for (int mi = 0; mi < 4; ++mi)
#pragma unroll
      for (int r = 0; r < 4; ++r) {
        int rl = wave * 64 + mi * 16 + quad * 4 + r;
#pragma unroll
        for (int ni = 0; ni < 4; ++ni) {
          float v = acc[mi][ni][r] + bv[ni];
          if (RELU) v = fmaxf(v, 0.f);
          Os[rl * 64 + ni * 16 + lm] = (bf16_t)v;
        }
      }
    __syncthreads();
#pragma unroll
    for (int i = 0; i < 8; ++i) {
      int fe = i * 2048 + t * 8;
      int rl = fe >> 6, cl = fe & 63;
      int row = m0 + rl, colg = n0 + cl;
      if (row < M && colg < N) {
        bf16x8 v8 = *(const bf16x8*)&Os[fe];
        if (NT) __builtin_nontemporal_store(v8, (bf16x8*)&C[(size_t)row * N + colg]);
        else *(bf16x8*)&C[(size_t)row * N + colg] = v8;
      }
    }
  }
}

// ---------------------------------------------------------------------------
// m97-style GEMM for FFN2 (K=1024)
// ---------------------------------------------------------------------------
template<typename AT, int EPI, typename OT>
__global__ __launch_bounds__(256) void gemm128(
    const AT* __restrict__ A, const bf16_t* __restrict__ W,
    const float* __restrict__ bias, OT* __restrict__ C,
    int M, int N, int K, int tiles_n)
{
  __shared__ __align__(16) bf16_t As[128 * 32];
  __shared__ __align__(16) bf16_t Bs[128 * 32];
  const int tm = blockIdx.x / tiles_n;
  const int tn = blockIdx.x - tm * tiles_n;
  const int m0 = tm << 7, n0 = tn << 7;
  const int t = threadIdx.x;
  const int wave = t >> 6, lane = t & 63;
  const int wr = wave >> 1, wc = wave & 1;
  const int lm = lane & 15, kq = lane >> 4;

  f32x4 acc[4][4];
#pragma unroll
  for (int i = 0; i < 4; ++i)
#pragma unroll
    for (int j = 0; j < 4; ++j) acc[i][j] = (f32x4){0.f, 0.f, 0.f, 0.f};

  for (int k0 = 0; k0 < K; k0 += 32) {
    __syncthreads();
#pragma unroll
    for (int i = 0; i < 2; ++i) {
      int flat = i * 4096 + t * 16;
      int row = flat >> 6;
      int cl = (flat >> 4) & 3;
      int cg = cl ^ ((row >> 1) & 3);
      int grow = m0 + row; if (grow >= M) grow = M - 1;
      async16(&A[(size_t)grow * K + k0 + cg * 8], (char*)As + flat);
    }
#pragma unroll
    for (int i = 0; i < 2; ++i) {
      int flat = i * 4096 + t * 16;
      int row = flat >> 6;
      int cl = (flat >> 4) & 3;
      int cg = cl ^ ((row >> 1) & 3);
      int grow = n0 + row; if (grow >= N) grow = N - 1;
      async16(&W[(size_t)grow * K + k0 + cg * 8], (char*)Bs + flat);
    }
    __syncthreads();

    bf16x8 af[4], bfr[4];
#pragma unroll
    for (int mi = 0; mi < 4; ++mi) {
      int row = wr * 64 + mi * 16 + lm;
      int s = (row >> 1) & 3;
      af[mi] = *(const bf16x8*)((const bf16_t*)As + row * 32 + ((kq ^ s) << 3));
    }
#pragma unroll
    for (int ni = 0; ni < 4; ++ni) {
      int row = wc * 64 + ni * 16 + lm;
      int s = (row >> 1) & 3;
      bfr[ni] = *(const bf16x8*)(Bs + row * 32 + ((kq ^ s) << 3));
    }
#pragma unroll
    for (int mi = 0; mi < 4; ++mi)
#pragma unroll
      for (int ni = 0; ni < 4; ++ni)
        acc[mi][ni] = __builtin_amdgcn_mfma_f32_16x16x32_bf16(af[mi], bfr[ni], acc[mi][ni], 0, 0, 0);
  }

  const int colb = n0 + wc * 64 + lm;
  float bv[4]; bool cok[4];
#pragma unroll
  for (int ni = 0; ni < 4; ++ni) {
    int c = colb + ni * 16;
    cok[ni] = (c < N);
    bv[ni] = cok[ni] ? bias[c] : 0.f;
  }
#pragma unroll
  for (int mi = 0; mi < 4; ++mi) {
    int rbase = m0 + wr * 64 + mi * 16 + kq * 4;
#pragma unroll
    for (int reg = 0; reg < 4; ++reg) {
      int r = rbase + reg;
      if (r < M) {
#pragma unroll
        for (int ni = 0; ni < 4; ++ni) if (cok[ni]) {
          float v = acc[mi][ni][reg] + bv[ni];
          if (EPI == 1) v = fmaxf(v, 0.f);
          C[(size_t)r * N + colb + ni * 16] = (OT)v;
        }
      }
    }
  }
}

// ---------------------------------------------------------------------------
// fused weight convert (8 matrices -> bf16) + off/aw bias concat (f32)
// ---------------------------------------------------------------------------
__global__ __launch_bounds__(256) void cvt_all(
    const float* __restrict__ s0, const float* __restrict__ s1,
    const float* __restrict__ s2, const float* __restrict__ s3,
    const float* __restrict__ s4, const float* __restrict__ s5,
    const float* __restrict__ s6, const float* __restrict__ s7,
    bf16_t* __restrict__ dst,
    const float* __restrict__ ob, const float* __restrict__ ab,
    float* __restrict__ bcat)
{
  int i = blockIdx.x * 256 + threadIdx.x;
  if (i < 130048) {
    const float* s; int base;
    if (i < 24576)      { s = s0; base = 0; }
    else if (i < 32768) { s = s1; base = 24576; }
    else if (i < 43008) { s = s2; base = 32768; }
    else if (i < 48128) { s = s3; base = 43008; }
    else if (i < 56320) { s = s4; base = 48128; }
    else if (i < 64512) { s = s5; base = 56320; }
    else if (i < 97280) { s = s6; base = 64512; }
    else                { s = s7; base = 97280; }
    int li = i - base;
    f32x4 x0 = ((const f32x4*)s)[2 * li], x1 = ((const f32x4*)s)[2 * li + 1];
    bf16x8 r;
#pragma unroll
    for (int j = 0; j < 4; ++j) { r[j] = (bf16_t)x0[j]; r[4 + j] = (bf16_t)x1[j]; }
    ((bf16x8*)dst)[i] = r;
  } else {
    int j = i - 130048;
    if (j < 480) bcat[j] = (j < 320) ? ob[j] : ab[j - 320];
  }
}

__global__ __launch_bounds__(256) void addpos_kernel(
    const float* __restrict__ a, const float* __restrict__ b,
    bf16_t* __restrict__ o, int n8)
{
  int i = blockIdx.x * 256 + threadIdx.x;
  if (i < n8) {
    f32x4 x0 = ((const f32x4*)a)[2 * i], x1 = ((const f32x4*)a)[2 * i + 1];
    f32x4 y0 = ((const f32x4*)b)[2 * i], y1 = ((const f32x4*)b)[2 * i + 1];
    bf16x8 r;
#pragma unroll
    for (int j = 0; j < 4; ++j) { r[j] = (bf16_t)(x0[j] + y0[j]); r[4 + j] = (bf16_t)(x1[j] + y1[j]); }
    ((bf16x8*)o)[i] = r;
  }
}

// ---------------------------------------------------------------------------
// residual + layernorm (f32 out, optional bf16 second output), D=256
// ---------------------------------------------------------------------------
template<int WBF>
__global__ __launch_bounds__(256) void lnres_kernel(
    const float* __restrict__ x, const float* __restrict__ res,
    const float* __restrict__ g, const float* __restrict__ bta,
    float* __restrict__ out, bf16_t* __restrict__ outb, int rows)
{
  int wave = threadIdx.x >> 6, lane = threadIdx.x & 63;
  int row = blockIdx.x * 4 + wave;
  if (row >= rows) return;
  const float4* xp = (const float4*)(x + (size_t)row * DD);
  const float4* rp = (const float4*)(res + (size_t)row * DD);
  float4 v = xp[lane], rr = rp[lane];
  float a0 = v.x + rr.x, a1 = v.y + rr.y, a2 = v.z + rr.z, a3 = v.w + rr.w;
  float s = a0 + a1 + a2 + a3;
#pragma unroll
  for (int off = 32; off; off >>= 1) s += __shfl_xor(s, off);
  float mean = s * (1.0f / DD);
  float d0 = a0 - mean, d1 = a1 - mean, d2 = a2 - mean, d3 = a3 - mean;
  float vs = d0 * d0 + d1 * d1 + d2 * d2 + d3 * d3;
#pragma unroll
  for (int off = 32; off; off >>= 1) vs += __shfl_xor(vs, off);
  float inv = rsqrtf(vs * (1.0f / DD) + 1e-5f);
  float4 gg = ((const float4*)g)[lane];
  float4 bb = ((const float4*)bta)[lane];
  float o0 = d0 * inv * gg.x + bb.x, o1 = d1 * inv * gg.y + bb.y;
  float o2 = d2 * inv * gg.z + bb.z, o3 = d3 * inv * gg.w + bb.w;
  float4 o; o.x = o0; o.y = o1; o.z = o2; o.w = o3;
  ((float4*)(out + (size_t)row * DD))[lane] = o;
  if (WBF) {
    bf16x4 ob; ob[0] = (bf16_t)o0; ob[1] = (bf16_t)o1; ob[2] = (bf16_t)o2; ob[3] = (bf16_t)o3;
    ((bf16x4*)(outb + (size_t)row * DD))[lane] = ob;
  }
}

// ---------------------------------------------------------------------------
// MFMA flash self-attention. Block = (b,h) x 64-q tile.
// ---------------------------------------------------------------------------
__global__ __launch_bounds__(256) void attn_mfma(
    const bf16_t* __restrict__ qk, const bf16_t* __restrict__ vp,
    bf16_t* __restrict__ sa)
{
  __shared__ __align__(16) bf16_t Ks[128 * 32];
  __shared__ __align__(16) bf16_t VT[32 * 136];
  __shared__ __align__(16) bf16_t Pw[4][16 * 136];
  const int bh = blockIdx.x;
  const int b = bh & 7, h = bh >> 3;
  const int qt = blockIdx.y;
  const int t = threadIdx.x, wave = t >> 6, lane = t & 63;
  const int lm = lane & 15, quad = lane >> 4;
  const int q0 = qt * 64 + wave * 16;

  int qrow = q0 + lm; if (qrow > NQ - 1) qrow = NQ - 1;
  bf16x8 aqr = *(const bf16x8*)&qk[((size_t)qrow * BB + b) * 512 + h * 32 + quad * 8];
  bf16x8 aq;
#pragma unroll
  for (int j = 0; j < 8; ++j) aq[j] = (bf16_t)((float)aqr[j] * 0.17677669529663687f);

  f32x4 m_run = {-1e30f, -1e30f, -1e30f, -1e30f};
  f32x4 l_run = {0.f, 0.f, 0.f, 0.f};
  f32x4 o0 = {0.f, 0.f, 0.f, 0.f}, o1 = {0.f, 0.f, 0.f, 0.f};
  const f32x4 zero = {0.f, 0.f, 0.f, 0.f};

  for (int c = 0; c < 8; ++c) {
    const int k0 = c * 128;
    __syncthreads();
#pragma unroll
    for (int i = 0; i < 2; ++i) {
      int flat = i * 4096 + t * 16;
      int row = flat >> 6;
      int cl = (flat >> 4) & 3;
      int cg = cl ^ ((row >> 1) & 3);
      int key = k0 + row; if (key > NQ - 1) key = NQ - 1;
      async16(&qk[((size_t)key * BB + b) * 512 + 256 + h * 32 + cg * 8], (char*)Ks + flat);
    }
#pragma unroll
    for (int i = 0; i < 2; ++i) {
      int idx = t * 2 + i;
      int key = idx >> 2, dc = idx & 3;
      int gk = k0 + key;
      if (gk < NQ) {
        bf16x8 vv = *(const bf16x8*)&vp[((size_t)gk * BB + b) * 256 + h * 32 + dc * 8];
#pragma unroll
        for (int u = 0; u < 8; ++u) VT[(dc * 8 + u) * 136 + key] = vv[u];
      } else {
#pragma unroll
        for (int u = 0; u < 8; ++u) VT[(dc * 8 + u) * 136 + key] = (bf16_t)0.f;
      }
    }
    __syncthreads();

    f32x4 s[8];
#pragma unroll
    for (int blk = 0; blk < 8; ++blk) {
      int row = blk * 16 + lm;
      int sw = (row >> 1) & 3;
      bf16x8 kb = *(const bf16x8*)&Ks[row * 32 + ((quad ^ sw) << 3)];
      s[blk] = __builtin_amdgcn_mfma_f32_16x16x32_bf16(aq, kb, zero, 0, 0, 0);
    }
    if (c == 7) {
#pragma unroll
      for (int blk = 0; blk < 8; ++blk) {
        if (k0 + blk * 16 + lm >= NQ) {
#pragma unroll
          for (int r = 0; r < 4; ++r) s[blk][r] = -1e30f;
        }
      }
    }
    f32x4 mx = s[0];
#pragma unroll
    for (int blk = 1; blk < 8; ++blk)
#pragma unroll
      for (int r = 0; r < 4; ++r) mx[r] = fmaxf(mx[r], s[blk][r]);
#pragma unroll
    for (int d = 1; d < 16; d <<= 1)
#pragma unroll
      for (int r = 0; r < 4; ++r) mx[r] = fmaxf(mx[r], __shfl_xor(mx[r], d));
    f32x4 m_new, alpha;
#pragma unroll
    for (int r = 0; r < 4; ++r) {
      m_new[r] = fmaxf(m_run[r], mx[r]);
      alpha[r] = __expf(m_run[r] - m_new[r]);
    }
    f32x4 psum = {0.f, 0.f, 0.f, 0.f};
#pragma unroll
    for (int blk = 0; blk < 8; ++blk) {
#pragma unroll
      for (int r = 0; r < 4; ++r) {
        float p = __expf(s[blk][r] - m_new[r]);
        psum[r] += p;
        Pw[wave][(quad * 4 + r) * 136 + blk * 16 + lm] = (bf16_t)p;
      }
    }
#pragma unroll
    for (int d = 1; d < 16; d <<= 1)
#pragma unroll
      for (int r = 0; r < 4; ++r) psum[r] += __shfl_xor(psum[r], d);
#pragma unroll
    for (int r = 0; r < 4; ++r) {
      l_run[r] = l_run[r] * alpha[r] + psum[r];
      m_run[r] = m_new[r];
      o0[r] *= alpha[r];
      o1[r] *= alpha[r];
    }
    bf16x8 ap[4];
#pragma unroll
    for (int kc = 0; kc < 4; ++kc)
      ap[kc] = *(const bf16x8*)&Pw[wave][lm * 136 + kc * 32 + quad * 8];
#pragma unroll
    for (int kc = 0; kc < 4; ++kc) {
      bf16x8 vb0 = *(const bf16x8*)&VT[lm * 136 + kc * 32 + quad * 8];
      bf16x8 vb1 = *(const bf16x8*)&VT[(16 + lm) * 136 + kc * 32 + quad * 8];
      o0 = __builtin_amdgcn_mfma_f32_16x16x32_bf16(ap[kc], vb0, o0, 0, 0, 0);
      o1 = __builtin_amdgcn_mfma_f32_16x16x32_bf16(ap[kc], vb1, o1, 0, 0, 0);
    }
  }
#pragma unroll
  for (int r = 0; r < 4; ++r) {
    int q = q0 + quad * 4 + r;
    if (q < NQ) {
      float inv = 1.0f / l_run[r];
      size_t base = ((size_t)q * BB + b) * 256 + h * 32;
      sa[base + lm] = (bf16_t)(o0[r] * inv);
      sa[base + 16 + lm] = (bf16_t)(o1[r] * inv);
    }
  }
}

// ---------------------------------------------------------------------------
// deformable sampling: block per row r=q*8+b; reads combined oa [7200,480]
// (cols 0..319 = offsets, 320..479 = aw logits); out bf16 [7200,256]
// ---------------------------------------------------------------------------
__global__ __launch_bounds__(256) void deform_kernel(
    const bf16_t* __restrict__ value, const float* __restrict__ oa,
    const float* __restrict__ refp, bf16_t* __restrict__ out)
{
  __shared__ float logits[160];
  __shared__ float wfin[160][4];
  __shared__ int   tidx[160][4];
  __shared__ float hmax[8], hsum[8];
  const int r = blockIdx.x;
  const int b = r & 7;
  const int t = threadIdx.x;
  if (t < 160) {
    int i20 = t % 20;
    int l = i20 / 5;
    logits[t] = oa[(size_t)r * 480 + 320 + t];
    float ox = oa[(size_t)r * 480 + t * 2];
    float oy = oa[(size_t)r * 480 + t * 2 + 1];
    const float* rp = refp + ((size_t)r * LL + l) * 4;
    int Wl = 128 >> l;
    int st = (l == 0) ? 0 : (l == 1) ? 16384 : (l == 2) ? 20480 : 21504;
    float lx = rp[0] + ox * 0.1f * rp[2];
    float ly = rp[1] + oy * 0.1f * rp[3];
    float xx = lx * (float)Wl - 0.5f;
    float yy = ly * (float)Wl - 0.5f;
    float x0f = floorf(xx), y0f = floorf(yy);
    float fx = xx - x0f, fy = yy - y0f;
    int x0 = (int)x0f, y0 = (int)y0f;
#pragma unroll
    for (int tap = 0; tap < 4; ++tap) {
      int dx = tap & 1, dy = tap >> 1;
      int xi = x0 + dx, yi = y0 + dy;
      float w = (dx ? fx : 1.0f - fx) * (dy ? fy : 1.0f - fy);
      bool valid = (xi >= 0) & (xi < Wl) & (yi >= 0) & (yi < Wl);
      int xc = min(max(xi, 0), Wl - 1);
      int yc = min(max(yi, 0), Wl - 1);
      tidx[t][tap] = (st + yc * Wl + xc) * BB + b;
      wfin[t][tap] = valid ? w : 0.0f;
    }
  }
  __syncthreads();
  if (t < 8) {
    float m = -1e30f;
    for (int i = 0; i < 20; ++i) m = fmaxf(m, logits[t * 20 + i]);
    float s = 0.f;
    for (int i = 0; i < 20; ++i) s += __expf(logits[t * 20 + i] - m);
    hmax[t] = m; hsum[t] = s;
  }
  __syncthreads();
  if (t < 160) {
    int h = t / 20;
    float p = __expf(logits[t] - hmax[h]) / hsum[h];
#pragma unroll
    for (int tap = 0; tap < 4; ++tap) wfin[t][tap] *= p;
  }
  __syncthreads();
  const int h = t >> 5, d = t & 31;
  const bf16_t* vbase = value + h * 32 + d;
  float acc = 0.f;
#pragma unroll 4
  for (int i = 0; i < 20; ++i) {
    int e = h * 20 + i;
#pragma unroll
    for (int tap = 0; tap < 4; ++tap) {
      float w = wfin[e][tap];
      float v = (float)vbase[(size_t)tidx[e][tap] * 256];
      acc = fmaf(w, v, acc);
    }
  }
  out[(size_t)r * 256 + t] = (bf16_t)acc;
}

// ---------------------------------------------------------------------------
// launch
// ---------------------------------------------------------------------------
static inline int tiles(int x) { return (x + 127) >> 7; }

extern "C" void kernel_launch(void* const* d_in, const int* in_sizes, int n_in,
                              void* d_out, int out_size, void* d_ws, size_t ws_size,
                              hipStream_t stream) {
  const float* tgt     = (const float*)d_in[0];
  const float* pos     = (const float*)d_in[1];
  const float* refp    = (const float*)d_in[2];
  const float* memory  = (const float*)d_in[3];
  const float* sa_in_w = (const float*)d_in[4];
  const float* sa_in_b = (const float*)d_in[5];
  const float* sa_out_w= (const float*)d_in[6];
  const float* sa_out_b= (const float*)d_in[7];
  const float* off_w   = (const float*)d_in[8];
  const float* off_b   = (const float*)d_in[9];
  const float* aw_w    = (const float*)d_in[10];
  const float* aw_b    = (const float*)d_in[11];
  const float* val_w   = (const float*)d_in[12];
  const float* val_b   = (const float*)d_in[13];
  const float* co_w    = (const float*)d_in[14];
  const float* co_b    = (const float*)d_in[15];
  const float* w1      = (const float*)d_in[16];
  const float* b1      = (const float*)d_in[17];
  const float* w2      = (const float*)d_in[18];
  const float* b2      = (const float*)d_in[19];
  const float* ln1_g   = (const float*)d_in[20];
  const float* ln1_b   = (const float*)d_in[21];
  const float* ln2_g   = (const float*)d_in[22];
  const float* ln2_b   = (const float*)d_in[23];
  const float* ln3_g   = (const float*)d_in[24];
  const float* ln3_b   = (const float*)d_in[25];

  char* ws = (char*)d_ws;
  bf16_t* value_bf = (bf16_t*)ws;                        // 89,128,960
  bf16_t* qk_bf    = (bf16_t*)(ws + 89128960);           // 7,372,800 | h1_bf 14,745,600
  bf16_t* h1_bf    = qk_bf;
  bf16_t* qsum_bf  = (bf16_t*)(ws + 103874560);          // 3,686,400
  bf16_t* vp_bf    = (bf16_t*)(ws + 107560960);          // 3,686,400
  bf16_t* sa_bf    = (bf16_t*)(ws + 111247360);          // 3,686,400
  float*  tgt2     = (float*)(ws + 114933760);           // 7,372,800
  bf16_t* query_bf = (bf16_t*)(ws + 122306560);          // 3,686,400
  float*  oa       = (float*)(ws + 125992960);           // 13,824,000 ([7200,480] off|aw)
  bf16_t* ca_bf    = (bf16_t*)(ws + 139816960);          // 3,686,400
  float*  gout     = (float*)(ws + 143503360);           // 7,372,800
  float*  tgt3     = (float*)(ws + 150876160);           // 7,372,800
  bf16_t* tgt3_bf  = (bf16_t*)(ws + 158248960);          // 3,686,400
  bf16_t* wbf      = (bf16_t*)(ws + 161935360);          // 2,080,768
  bf16_t* sa_in_wb = wbf;
  bf16_t* sa_out_wb= wbf + 196608;
  bf16_t* oa_wb    = wbf + 262144;                       // off_w|aw_w contiguous (N=480)
  bf16_t* val_wb   = wbf + 385024;
  bf16_t* co_wb    = wbf + 450560;
  bf16_t* w1b      = wbf + 516096;
  bf16_t* w2b      = wbf + 778240;
  float*  oabias   = (float*)(ws + 164016128);           // 1,920
  float*  outp     = (float*)d_out;

  const int n8q = MQ * DD / 8;
  const int mtq = (MQ + 255) >> 8;   // 29

  cvt_all<<<dim3(510), 256, 0, stream>>>(
      sa_in_w, sa_out_w, off_w, aw_w, val_w, co_w, w1, w2, wbf,
      off_b, aw_b, oabias);

  // ---- self-attention ----
  addpos_kernel<<<dim3((n8q + 255) / 256), 256, 0, stream>>>(tgt, pos, qsum_bf, n8q);
  vgemm<bf16_t, bf16_t, 0, 0, 0><<<dim3(mtq * 8), 256, 0, stream>>>(
      qsum_bf, sa_in_wb, sa_in_b, qk_bf, MQ, 512, 8);
  vgemm<float, bf16_t, 0, 0, 0><<<dim3(mtq * 4), 256, 0, stream>>>(
      tgt, sa_in_wb + 512 * 256, sa_in_b + 512, vp_bf, MQ, 256, 4);
  attn_mfma<<<dim3(64, 15), 256, 0, stream>>>(qk_bf, vp_bf, sa_bf);
  vgemm<bf16_t, float, 0, 0, 0><<<dim3(mtq * 4), 256, 0, stream>>>(
      sa_bf, sa_out_wb, sa_out_b, gout, MQ, 256, 4);
  lnres_kernel<0><<<dim3((MQ + 3) / 4), 256, 0, stream>>>(
      gout, tgt, ln2_g, ln2_b, tgt2, (bf16_t*)nullptr, MQ);

  // ---- deformable cross-attention ----
  addpos_kernel<<<dim3((n8q + 255) / 256), 256, 0, stream>>>(tgt2, pos, query_bf, n8q);
  // value GEMM: XCD-sibling swizzle (680 row tiles = 85*8), NT stores
  vgemm<float, bf16_t, 0, 1, 1><<<dim3(680 * 4), 256, 0, stream>>>(
      memory, val_wb, val_b, value_bf, MV, 256, 4);
  // merged offsets+aw GEMM, N=480
  vgemm<bf16_t, float, 0, 0, 0><<<dim3(mtq * 8), 256, 0, stream>>>(
      query_bf, oa_wb, oabias, oa, MQ, 480, 8);
  deform_kernel<<<dim3(MQ), 256, 0, stream>>>(value_bf, oa, refp, ca_bf);
  vgemm<bf16_t, float, 0, 0, 0><<<dim3(mtq * 4), 256, 0, stream>>>(
      ca_bf, co_wb, co_b, gout, MQ, 256, 4);
  lnres_kernel<1><<<dim3((MQ + 3) / 4), 256, 0, stream>>>(
      gout, tgt2, ln1_g, ln1_b, tgt3, tgt3_bf, MQ);

  // ---- FFN ----
  vgemm<bf16_t, bf16_t, 1, 0, 0><<<dim3(mtq * 16), 256, 0, stream>>>(
      tgt3_bf, w1b, b1, h1_bf, MQ, 1024, 16);
  gemm128<bf16_t, 0, float><<<dim3(tiles(MQ) * 2), 256, 0, stream>>>(
      h1_bf, w2b, b2, gout, MQ, 256, DFF, 2);
  lnres_kernel<0><<<dim3((MQ + 3) / 4), 256, 0, stream>>>(
      gout, tgt3, ln3_g, ln3_b, outp, (bf16_t*)nullptr, MQ);

  (void)in_sizes; (void)n_in; (void)out_size; (void)ws_size;
}